// Round 4
// baseline (1148.426 us; speedup 1.0000x reference)
//
#include <hip/hip_runtime.h>
#include <hip/hip_bf16.h>
#include <type_traits>

#define BB 4
#define CC 64
#define HH 192
#define WW 192
#define HWSZ (HH*WW)          // 36864
#define GG 32
#define BLKS_PER_B (HWSZ/256) // 144

__device__ __forceinline__ float to_f(__hip_bfloat16 v) { return __bfloat162float(v); }
__device__ __forceinline__ float to_f(float v) { return v; }

// ---- dtype detector: bf16 data has sane bf16 exponents in BOTH 16-bit halves of
// ---- each 32-bit word; fp32 data's low half is random mantissa bits. Vote 256 words.
__global__ __launch_bounds__(256) void k_detect(const unsigned* __restrict__ xw,
                                                int* __restrict__ flag,
                                                unsigned* __restrict__ mm) {
    int t = threadIdx.x;
    if (t < 2*BB) mm[t] = (t & 1) ? 0u : 0x7F800000u; // even=min(+inf bits), odd=max(0)
    __shared__ int cnt[256];
    unsigned w = xw[t];
    unsigned lo = w & 0xFFFFu;
    unsigned e = (lo >> 7) & 0xFFu;
    cnt[t] = (lo == 0u || (e >= 100u && e <= 140u)) ? 1 : 0;
    __syncthreads();
    for (int o = 128; o > 0; o >>= 1) {
        if (t < o) cnt[t] += cnt[t+o];
        __syncthreads();
    }
    if (t == 0) flag[0] = (cnt[0] >= 128) ? 1 : 0;
}

// ---------------- GroupNorm stats: 1 block per (b,g) ----------------
template <typename T>
__device__ __forceinline__ void gn_body(const T* __restrict__ x, float* __restrict__ gn) {
    __shared__ float ss[256], sq2[256];
    int bg = blockIdx.x;                              // b*32+g
    const T* p = x + (size_t)bg * 2 * HWSZ;
    float s = 0.f, q = 0.f;
    for (int i = threadIdx.x; i < 2*HWSZ; i += 256) {
        float v = to_f(p[i]); s += v; q += v*v;
    }
    ss[threadIdx.x] = s; sq2[threadIdx.x] = q;
    __syncthreads();
    for (int o = 128; o > 0; o >>= 1) {
        if (threadIdx.x < o) {
            ss[threadIdx.x]  += ss[threadIdx.x+o];
            sq2[threadIdx.x] += sq2[threadIdx.x+o];
        }
        __syncthreads();
    }
    if (threadIdx.x == 0) {
        float mu  = ss[0]  / (2.f*HWSZ);
        float var = sq2[0] / (2.f*HWSZ) - mu*mu;
        gn[bg*2]   = mu;
        gn[bg*2+1] = rsqrtf(var + 1e-5f);
    }
}
__global__ __launch_bounds__(256) void k_gn(const void* x, float* gn, const int* flag) {
    if (*flag) gn_body((const __hip_bfloat16*)x, gn);
    else       gn_body((const float*)x, gn);
}

// ---- df = sum_c |x - up(down(x))| with down/up recomputed on the fly; also ||x||_c ----
template <typename T>
__device__ __forceinline__ void df_body(const T* __restrict__ x,
                                        float* __restrict__ df, float* __restrict__ nrm,
                                        unsigned* __restrict__ mm) {
    int b = blockIdx.x / BLKS_PER_B;
    int p = (blockIdx.x % BLKS_PER_B) * 256 + threadIdx.x;
    int h = p / WW, w = p % WW;
    // half-pixel source coords for 96->192 upsample (ref: H axis first, then W)
    float hs = fminf(fmaxf(0.5f*(float)h - 0.25f, 0.f), 95.f);
    float wsr= fminf(fmaxf(0.5f*(float)w - 0.25f, 0.f), 95.f);
    int hl = (int)hs; int hh2 = min(hl+1, 95); float fh = hs - (float)hl;
    int wl = (int)wsr; int wh2 = min(wl+1, 95); float fw = wsr - (float)wl;
    int r0 = 2*hl, r1 = 2*hh2, q0 = 2*wl, q1 = 2*wh2;

    const T* xb = x + (size_t)b*CC*HWSZ;
    float s = 0.f, sq = 0.f;
    for (int c = 0; c < CC; ++c) {
        const T* pc = xb + (size_t)c*HWSZ;
        float xc = to_f(pc[p]);
        const T* a0 = pc + r0*WW;
        const T* a1 = pc + r1*WW;
        float v00 = 0.25f*(to_f(a0[q0])+to_f(a0[q0+1])+to_f(a0[q0+WW])+to_f(a0[q0+WW+1]));
        float v01 = 0.25f*(to_f(a0[q1])+to_f(a0[q1+1])+to_f(a0[q1+WW])+to_f(a0[q1+WW+1]));
        float v10 = 0.25f*(to_f(a1[q0])+to_f(a1[q0+1])+to_f(a1[q0+WW])+to_f(a1[q0+WW+1]));
        float v11 = 0.25f*(to_f(a1[q1])+to_f(a1[q1+1])+to_f(a1[q1+WW])+to_f(a1[q1+WW+1]));
        float t0 = (1.f-fh)*v00 + fh*v10;   // H lerp first
        float t1 = (1.f-fh)*v01 + fh*v11;
        float du = (1.f-fw)*t0 + fw*t1;     // then W
        s  += fabsf(xc - du);
        sq += xc*xc;
    }
    df[b*HWSZ+p]  = s;
    nrm[b*HWSZ+p] = sqrtf(sq);

    __shared__ float smin[256], smax[256];
    smin[threadIdx.x] = s; smax[threadIdx.x] = s;
    __syncthreads();
    for (int o = 128; o > 0; o >>= 1) {
        if (threadIdx.x < o) {
            smin[threadIdx.x] = fminf(smin[threadIdx.x], smin[threadIdx.x+o]);
            smax[threadIdx.x] = fmaxf(smax[threadIdx.x], smax[threadIdx.x+o]);
        }
        __syncthreads();
    }
    if (threadIdx.x == 0) {
        atomicMin(&mm[2*b],   __float_as_uint(smin[0]));
        atomicMax(&mm[2*b+1], __float_as_uint(smax[0]));
    }
}
__global__ __launch_bounds__(256) void k_df(const void* x, float* df, float* nrm,
                                            unsigned* mm, const int* flag) {
    if (*flag) df_body((const __hip_bfloat16*)x, df, nrm, mm);
    else       df_body((const float*)x, df, nrm, mm);
}

// ------- fused: sims + adaptive top-k softmax + GN affine + FFN + residual -------
template <typename T>
__device__ __forceinline__ void fused_body(const T* __restrict__ x,
                                           const float* __restrict__ df,
                                           const float* __restrict__ nrm,
                                           const unsigned* __restrict__ mm,
                                           const float* __restrict__ gn,
                                           const T* __restrict__ gw,
                                           const T* __restrict__ gb,
                                           const T* __restrict__ w1,
                                           const T* __restrict__ b1,
                                           const T* __restrict__ w2,
                                           const T* __restrict__ b2,
                                           T* __restrict__ out) {
    __shared__ float sw1[128*64];   // [j][c] row-major (as given)
    __shared__ float sw2[128*64];   // transposed: sw2[j*64+c] = w2[c][j]
    for (int i = threadIdx.x; i < 128*64; i += 256) {
        sw1[i] = to_f(w1[i]);
        int c = i / 128, j = i % 128;        // w2 is [C][2C] row-major
        sw2[j*64 + c] = to_f(w2[i]);
    }
    // no LDS reads until after __syncthreads below

    int b = blockIdx.x / BLKS_PER_B;
    int p = (blockIdx.x % BLKS_PER_B) * 256 + threadIdx.x;
    int h = p / WW, w = p % WW;

    float dmin = __uint_as_float(mm[2*b]);
    float dmax = __uint_as_float(mm[2*b+1]);
    float dfp = (df[b*HWSZ+p] - dmin) / (dmax - dmin + 1e-8f);
    dfp = dfp * dfp;
    bool mask = dfp > 0.3f;
    float conn = 1.f + (mask ? fmaxf(rintf(dfp * 15.f), 0.f) : 0.f);
    bool process = conn > 1.f;
    int kk = (int)fminf(conn, 9.f);

    const T* xb = x + (size_t)b*CC*HWSZ + p;

    const int dh[9] = {-1,-1,-1, 0,0,0, 1,1,1};
    const int dw[9] = {-1, 0, 1,-1,0,1,-1,0,1};
    bool valid[9]; int off[9];
    #pragma unroll
    for (int j = 0; j < 9; ++j) {
        int hn = h + dh[j], wn = w + dw[j];
        valid[j] = (hn >= 0) && (hn < HH) && (wn >= 0) && (wn < WW);
        off[j] = dh[j]*WW + dw[j];
    }

    float wt[9];
    #pragma unroll
    for (int j = 0; j < 9; ++j) wt[j] = 0.f;

    if (process) {
        float dot[9];
        #pragma unroll
        for (int j = 0; j < 9; ++j) dot[j] = 0.f;
        for (int c = 0; c < CC; ++c) {
            const T* pc = xb + (size_t)c*HWSZ;
            float xc = to_f(pc[0]);
            #pragma unroll
            for (int j = 0; j < 9; ++j)
                if (valid[j]) dot[j] += xc * to_f(pc[off[j]]);
        }
        float nc = fmaxf(nrm[b*HWSZ+p], 1e-12f);
        float sim[9];
        #pragma unroll
        for (int j = 0; j < 9; ++j) {
            if (valid[j]) {
                float nj = fmaxf(nrm[b*HWSZ+p+off[j]], 1e-12f);
                sim[j] = dot[j] / (nc * nj);
            } else sim[j] = 0.f;   // zero-pad patch => exact 0; ties broken by index
        }
        float S = 0.f;
        #pragma unroll
        for (int j = 0; j < 9; ++j) {
            int rank = 0;
            #pragma unroll
            for (int l = 0; l < 9; ++l)
                rank += (sim[l] > sim[j]) || (sim[l] == sim[j] && l < j);
            float e = (rank < kk) ? expf(sim[j]) : 0.f;   // stable top-k like argsort(-sim)
            wt[j] = e; S += e;
        }
        float inv = 1.f / fmaxf(S, 1e-12f);
        #pragma unroll
        for (int j = 0; j < 9; ++j) wt[j] *= inv;
    }

    // ---- enhanced = output + groupnorm affine, all 64 channels in registers ----
    float e[64];
    #pragma unroll
    for (int c = 0; c < CC; ++c) {
        const T* pc = xb + (size_t)c*HWSZ;
        float xc = to_f(pc[0]);
        float oc;
        if (process) {
            float acc = 0.f;
            #pragma unroll
            for (int j = 0; j < 9; ++j)
                if (valid[j]) acc += wt[j] * to_f(pc[off[j]]);
            oc = acc;
        } else {
            oc = xc;
        }
        int g = c >> 1;
        float mu = gn[(b*GG+g)*2], is = gn[(b*GG+g)*2+1];
        float nx = (xc - mu) * is * to_f(gw[c]) + to_f(gb[c]);
        e[c] = oc + nx;
    }

    __syncthreads();   // LDS weights ready

    // ---- FFN: out = e + w2 @ relu(w1 @ e + b1) + b2 ----
    float acc[64];
    #pragma unroll
    for (int c = 0; c < 64; ++c) acc[c] = e[c] + to_f(b2[c]);
    for (int j = 0; j < 128; ++j) {
        float hv = to_f(b1[j]);
        const float4* r1 = (const float4*)(&sw1[j*64]);
        #pragma unroll
        for (int q = 0; q < 16; ++q) {
            float4 v = r1[q];
            hv += v.x*e[4*q] + v.y*e[4*q+1] + v.z*e[4*q+2] + v.w*e[4*q+3];
        }
        hv = fmaxf(hv, 0.f);
        const float4* r2 = (const float4*)(&sw2[j*64]);
        #pragma unroll
        for (int q = 0; q < 16; ++q) {
            float4 v = r2[q];
            acc[4*q]   += v.x*hv;
            acc[4*q+1] += v.y*hv;
            acc[4*q+2] += v.z*hv;
            acc[4*q+3] += v.w*hv;
        }
    }
    T* ob = out + (size_t)b*CC*HWSZ + p;
    #pragma unroll
    for (int c = 0; c < 64; ++c) {
        if constexpr (std::is_same<T, float>::value) ob[(size_t)c*HWSZ] = acc[c];
        else ob[(size_t)c*HWSZ] = __float2bfloat16(acc[c]);
    }
}
__global__ __launch_bounds__(256) void k_fused(const void* x, const float* df,
                                               const float* nrm, const unsigned* mm,
                                               const float* gn,
                                               const void* gw, const void* gb,
                                               const void* w1, const void* b1,
                                               const void* w2, const void* b2,
                                               void* out, const int* flag) {
    if (*flag)
        fused_body((const __hip_bfloat16*)x, df, nrm, mm, gn,
                   (const __hip_bfloat16*)gw, (const __hip_bfloat16*)gb,
                   (const __hip_bfloat16*)w1, (const __hip_bfloat16*)b1,
                   (const __hip_bfloat16*)w2, (const __hip_bfloat16*)b2,
                   (__hip_bfloat16*)out);
    else
        fused_body((const float*)x, df, nrm, mm, gn,
                   (const float*)gw, (const float*)gb,
                   (const float*)w1, (const float*)b1,
                   (const float*)w2, (const float*)b2,
                   (float*)out);
}

extern "C" void kernel_launch(void* const* d_in, const int* in_sizes, int n_in,
                              void* d_out, int out_size, void* d_ws, size_t ws_size,
                              hipStream_t stream) {
    const void* x  = d_in[0];
    const void* gw = d_in[1];
    const void* gb = d_in[2];
    const void* w1 = d_in[3];
    const void* b1 = d_in[4];
    const void* w2 = d_in[5];
    const void* b2 = d_in[6];

    // ws layout (floats): df 147456 | nrm 147456 | gn 256 | mm 8u | flag 1i  (~1.18 MB)
    float* ws   = (float*)d_ws;
    float* df   = ws;
    float* nrm  = df + 147456;
    float* gn   = nrm + 147456;
    unsigned* mm = (unsigned*)(gn + 256);
    int* flag   = (int*)(mm + 8);

    k_detect<<<1, 256, 0, stream>>>((const unsigned*)x, flag, mm);
    k_gn   <<<BB*GG, 256, 0, stream>>>(x, gn, flag);
    k_df   <<<BB*BLKS_PER_B, 256, 0, stream>>>(x, df, nrm, mm, flag);
    k_fused<<<BB*BLKS_PER_B, 256, 0, stream>>>(x, df, nrm, mm, gn, gw, gb,
                                               w1, b1, w2, b2, d_out, flag);
}

// Round 5
// 586.532 us; speedup vs baseline: 1.9580x; 1.9580x over previous
//
#include <hip/hip_runtime.h>
#include <hip/hip_bf16.h>

#define BB 4
#define CC 64
#define HH 192
#define WW 192
#define HWSZ (HH*WW)          // 36864
#define GG 32
#define PBLK 128              // pixels per block (2 threads/pixel, 256 threads)
#define BPB (HWSZ/PBLK)       // 288 blocks per batch

// bf16 pack/unpack (RNE, no NaN inputs expected)
__device__ __forceinline__ unsigned short f2bf(float f) {
    unsigned u = __float_as_uint(f);
    return (unsigned short)((u + 0x7FFFu + ((u >> 16) & 1u)) >> 16);
}
__device__ __forceinline__ float bl(unsigned u) { return __uint_as_float(u << 16); }
__device__ __forceinline__ float bh(unsigned u) { return __uint_as_float(u & 0xFFFF0000u); }

// ---------------- GroupNorm stats (1 block per (b,g)); block 0 also inits mm ----------------
__global__ __launch_bounds__(256) void k_gn(const float* __restrict__ x,
                                            float* __restrict__ gn,
                                            unsigned* __restrict__ mm) {
    if (blockIdx.x == 0 && threadIdx.x < 2*BB)
        mm[threadIdx.x] = (threadIdx.x & 1) ? 0u : 0x7F800000u; // even=min(+inf), odd=max(0)
    __shared__ float ss[256], sq2[256];
    int bg = blockIdx.x;                              // b*32+g
    const float* p = x + (size_t)bg * 2 * HWSZ;
    float s = 0.f, q = 0.f;
    for (int i = threadIdx.x; i < 2*HWSZ; i += 256) {
        float v = p[i]; s += v; q += v*v;
    }
    ss[threadIdx.x] = s; sq2[threadIdx.x] = q;
    __syncthreads();
    for (int o = 128; o > 0; o >>= 1) {
        if (threadIdx.x < o) {
            ss[threadIdx.x]  += ss[threadIdx.x+o];
            sq2[threadIdx.x] += sq2[threadIdx.x+o];
        }
        __syncthreads();
    }
    if (threadIdx.x == 0) {
        float mu  = ss[0]  / (2.f*HWSZ);
        float var = sq2[0] / (2.f*HWSZ) - mu*mu;
        gn[bg*2]   = mu;
        gn[bg*2+1] = rsqrtf(var + 1e-5f);
    }
}

// ---- df = sum_c |x - up(down(x))|, down/up recomputed on the fly; also ||x||_c ----
// 2 threads per pixel: lanes 0-31 = channels 0-31, lanes 32-63 = channels 32-63.
__global__ __launch_bounds__(256) void k_df(const float* __restrict__ x,
                                            float* __restrict__ df,
                                            float* __restrict__ nrm,
                                            unsigned* __restrict__ mm) {
    int b = blockIdx.x / BPB;
    int pb = blockIdx.x % BPB;
    int lane = threadIdx.x & 63, wave = threadIdx.x >> 6;
    int half = lane >> 5;
    int p = pb*PBLK + wave*32 + (lane & 31);
    int h = p / WW, w = p % WW;
    // half-pixel source coords for 96->192 upsample (ref: H axis lerp first, then W)
    float hs = fminf(fmaxf(0.5f*(float)h - 0.25f, 0.f), 95.f);
    float wsr= fminf(fmaxf(0.5f*(float)w - 0.25f, 0.f), 95.f);
    int hl = (int)hs; int hh2 = min(hl+1, 95); float fh = hs - (float)hl;
    int wl = (int)wsr; int wh2 = min(wl+1, 95); float fw = wsr - (float)wl;
    int r0 = 2*hl, r1 = 2*hh2, q0 = 2*wl, q1 = 2*wh2;

    const float* xb = x + (size_t)b*CC*HWSZ;
    float s = 0.f, sq = 0.f;
    for (int cc = 0; cc < 32; ++cc) {
        const float* pc = xb + (size_t)(32*half + cc)*HWSZ;
        float xc = pc[p];
        const float* a0 = pc + r0*WW;
        const float* a1 = pc + r1*WW;
        float v00 = 0.25f*(a0[q0]+a0[q0+1]+a0[q0+WW]+a0[q0+WW+1]);
        float v01 = 0.25f*(a0[q1]+a0[q1+1]+a0[q1+WW]+a0[q1+WW+1]);
        float v10 = 0.25f*(a1[q0]+a1[q0+1]+a1[q0+WW]+a1[q0+WW+1]);
        float v11 = 0.25f*(a1[q1]+a1[q1+1]+a1[q1+WW]+a1[q1+WW+1]);
        float t0 = (1.f-fh)*v00 + fh*v10;   // H lerp first
        float t1 = (1.f-fh)*v01 + fh*v11;
        float du = (1.f-fw)*t0 + fw*t1;     // then W
        s  += fabsf(xc - du);
        sq += xc*xc;
    }
    // combine halves (partners always both active)
    s  += __shfl_xor(s, 32);
    sq += __shfl_xor(sq, 32);
    if (half == 0) {
        df[b*HWSZ+p]  = s;
        nrm[b*HWSZ+p] = sqrtf(sq);
    }

    __shared__ float smin[256], smax[256];
    smin[threadIdx.x] = s; smax[threadIdx.x] = s;   // duplicates don't affect min/max
    __syncthreads();
    for (int o = 128; o > 0; o >>= 1) {
        if (threadIdx.x < o) {
            smin[threadIdx.x] = fminf(smin[threadIdx.x], smin[threadIdx.x+o]);
            smax[threadIdx.x] = fmaxf(smax[threadIdx.x], smax[threadIdx.x+o]);
        }
        __syncthreads();
    }
    if (threadIdx.x == 0) {
        atomicMin(&mm[2*b],   __float_as_uint(smin[0]));
        atomicMax(&mm[2*b+1], __float_as_uint(smax[0]));
    }
}

// ------- fused: sims + adaptive top-k softmax + GN affine + FFN + residual -------
// 2 threads/pixel (32 channels each); weights staged bf16-packed in LDS (~35 KB).
__global__ __launch_bounds__(256) void k_fused(const float* __restrict__ x,
                                               const float* __restrict__ df,
                                               const float* __restrict__ nrm,
                                               const unsigned* __restrict__ mm,
                                               const float* __restrict__ gn,
                                               const float* __restrict__ gw,
                                               const float* __restrict__ gb,
                                               const float* __restrict__ w1,
                                               const float* __restrict__ b1,
                                               const float* __restrict__ w2,
                                               const float* __restrict__ b2,
                                               float* __restrict__ out) {
    // sw1u[j][m]: uint m packs w1[j][2m] (lo) | w1[j][2m+1] (hi); row stride 32 uints
    __shared__ __align__(16) unsigned sw1u[128*32];
    // sw2u: ushort rows of 72 (uint stride 36, 16B-aligned rows); sw2[j*72+c] = bf16(w2[c][j])
    __shared__ __align__(16) unsigned sw2u[128*36];
    __shared__ float sb1[128];
    for (int i = threadIdx.x; i < 4096; i += 256) {
        float2 v = ((const float2*)w1)[i];                 // j=i/32, channel pair 2(i%32)
        sw1u[i] = (unsigned)f2bf(v.x) | ((unsigned)f2bf(v.y) << 16);
    }
    for (int i = threadIdx.x; i < 8192; i += 256) {
        int c = i >> 7, j = i & 127;                       // w2 row-major [c][j]
        ((unsigned short*)sw2u)[j*72 + c] = f2bf(w2[i]);   // bank step 2 per lane: free
    }
    if (threadIdx.x < 128) sb1[threadIdx.x] = b1[threadIdx.x];
    // (single __syncthreads below, before FFN reads)

    int b = blockIdx.x / BPB;
    int pb = blockIdx.x % BPB;
    int lane = threadIdx.x & 63, wave = threadIdx.x >> 6;
    int half = lane >> 5;
    int p = pb*PBLK + wave*32 + (lane & 31);
    int h = p / WW, w = p % WW;
    int cbase = 32*half;

    float dmin = __uint_as_float(mm[2*b]);
    float dmax = __uint_as_float(mm[2*b+1]);
    float dfp = (df[b*HWSZ+p] - dmin) / (dmax - dmin + 1e-8f);
    dfp = dfp * dfp;
    bool mask = dfp > 0.3f;
    float conn = 1.f + (mask ? fmaxf(rintf(dfp * 15.f), 0.f) : 0.f);
    bool process = conn > 1.f;
    int kk = (int)fminf(conn, 9.f);

    const float* xb = x + (size_t)b*CC*HWSZ + p;

    const int dh[9] = {-1,-1,-1, 0,0,0, 1,1,1};
    const int dw[9] = {-1, 0, 1,-1,0,1,-1,0,1};
    bool valid[9]; int off[9];
    #pragma unroll
    for (int j = 0; j < 9; ++j) {
        int hn = h + dh[j], wn = w + dw[j];
        valid[j] = (hn >= 0) && (hn < HH) && (wn >= 0) && (wn < WW);
        off[j] = dh[j]*WW + dw[j];
    }

    float wt[9];
    #pragma unroll
    for (int j = 0; j < 9; ++j) wt[j] = 0.f;

    if (process) {
        float dot[9];
        #pragma unroll
        for (int j = 0; j < 9; ++j) dot[j] = 0.f;
        for (int cc = 0; cc < 32; ++cc) {
            const float* pc = xb + (size_t)(cbase + cc)*HWSZ;
            float xc = pc[0];
            #pragma unroll
            for (int j = 0; j < 9; ++j)
                if (valid[j]) dot[j] += xc * pc[off[j]];
        }
        #pragma unroll
        for (int j = 0; j < 9; ++j)
            dot[j] += __shfl_xor(dot[j], 32);   // partner shares `process`
        float nc = fmaxf(nrm[b*HWSZ+p], 1e-12f);
        float sim[9];
        #pragma unroll
        for (int j = 0; j < 9; ++j) {
            if (valid[j]) {
                float nj = fmaxf(nrm[b*HWSZ+p+off[j]], 1e-12f);
                sim[j] = dot[j] / (nc * nj);
            } else sim[j] = 0.f;   // zero-pad patch => exact 0; index tie-break below
        }
        float S = 0.f;
        #pragma unroll
        for (int j = 0; j < 9; ++j) {
            int rank = 0;
            #pragma unroll
            for (int l = 0; l < 9; ++l)
                rank += (sim[l] > sim[j]) || (sim[l] == sim[j] && l < j);
            float e = (rank < kk) ? expf(sim[j]) : 0.f;   // stable top-k == argsort(-sim)
            wt[j] = e; S += e;
        }
        float inv = 1.f / fmaxf(S, 1e-12f);
        #pragma unroll
        for (int j = 0; j < 9; ++j) wt[j] *= inv;
    }

    // ---- enhanced = weighted/identity + GN affine, own 32 channels in registers ----
    float e[32];
    for (int cc = 0; cc < 32; ++cc) {
        int c = cbase + cc;
        const float* pc = xb + (size_t)c*HWSZ;
        float xc = pc[0];
        float oc;
        if (process) {
            float acc = 0.f;
            #pragma unroll
            for (int j = 0; j < 9; ++j)
                if (valid[j]) acc += wt[j] * pc[off[j]];
            oc = acc;
        } else {
            oc = xc;
        }
        int g = c >> 1;
        float mu = gn[(b*GG+g)*2], is = gn[(b*GG+g)*2+1];
        e[cc] = oc + (xc - mu) * is * gw[c] + gb[c];
    }

    __syncthreads();   // LDS weights ready

    // ---- FFN: out = e + w2 @ relu(w1 @ e + b1) + b2 ----
    float acc[32];
    #pragma unroll
    for (int cc = 0; cc < 32; ++cc) acc[cc] = e[cc] + b2[cbase + cc];
    for (int j = 0; j < 128; ++j) {
        const uint4* r1 = (const uint4*)&sw1u[j*32 + 16*half];
        float hv = 0.f;
        #pragma unroll
        for (int q = 0; q < 4; ++q) {
            uint4 u = r1[q];
            hv += bl(u.x)*e[8*q]   + bh(u.x)*e[8*q+1]
                + bl(u.y)*e[8*q+2] + bh(u.y)*e[8*q+3]
                + bl(u.z)*e[8*q+4] + bh(u.z)*e[8*q+5]
                + bl(u.w)*e[8*q+6] + bh(u.w)*e[8*q+7];
        }
        hv += __shfl_xor(hv, 32);          // all lanes active here
        hv = fmaxf(hv + sb1[j], 0.f);
        const uint4* r2 = (const uint4*)&sw2u[j*36 + 16*half];
        #pragma unroll
        for (int q = 0; q < 4; ++q) {
            uint4 u = r2[q];
            acc[8*q]   += bl(u.x)*hv; acc[8*q+1] += bh(u.x)*hv;
            acc[8*q+2] += bl(u.y)*hv; acc[8*q+3] += bh(u.y)*hv;
            acc[8*q+4] += bl(u.z)*hv; acc[8*q+5] += bh(u.z)*hv;
            acc[8*q+6] += bl(u.w)*hv; acc[8*q+7] += bh(u.w)*hv;
        }
    }
    float* ob = out + (size_t)b*CC*HWSZ + (size_t)cbase*HWSZ + p;
    #pragma unroll
    for (int cc = 0; cc < 32; ++cc) ob[(size_t)cc*HWSZ] = acc[cc];
}

extern "C" void kernel_launch(void* const* d_in, const int* in_sizes, int n_in,
                              void* d_out, int out_size, void* d_ws, size_t ws_size,
                              hipStream_t stream) {
    const float* x  = (const float*)d_in[0];
    const float* gw = (const float*)d_in[1];
    const float* gb = (const float*)d_in[2];
    const float* w1 = (const float*)d_in[3];
    const float* b1 = (const float*)d_in[4];
    const float* w2 = (const float*)d_in[5];
    const float* b2 = (const float*)d_in[6];
    float* out = (float*)d_out;

    // ws layout (floats): df 147456 | nrm 147456 | gn 256 | mm 8u  (~1.18 MB)
    float* ws   = (float*)d_ws;
    float* df   = ws;
    float* nrm  = df + 147456;
    float* gn   = nrm + 147456;
    unsigned* mm = (unsigned*)(gn + 256);

    k_gn   <<<BB*GG, 256, 0, stream>>>(x, gn, mm);
    k_df   <<<BB*BPB, 256, 0, stream>>>(x, df, nrm, mm);
    k_fused<<<BB*BPB, 256, 0, stream>>>(x, df, nrm, mm, gn, gw, gb,
                                        w1, b1, w2, b2, out);
}

// Round 6
// 528.450 us; speedup vs baseline: 2.1732x; 1.1099x over previous
//
#include <hip/hip_runtime.h>
#include <hip/hip_bf16.h>

#define BB 4
#define CC 64
#define HH 192
#define WW 192
#define HWSZ (HH*WW)          // 36864
#define HD 96
#define WD 96
#define GG 32
#define PBLK 128              // pixels per block (2 threads/pixel, 256 threads)
#define BPB (HWSZ/PBLK)       // 288 blocks per batch

// bf16 pack/unpack (RNE)
__device__ __forceinline__ unsigned short f2bf(float f) {
    unsigned u = __float_as_uint(f);
    return (unsigned short)((u + 0x7FFFu + ((u >> 16) & 1u)) >> 16);
}
__device__ __forceinline__ float bl(unsigned u) { return __uint_as_float(u << 16); }
__device__ __forceinline__ float bh(unsigned u) { return __uint_as_float(u & 0xFFFF0000u); }

__device__ __forceinline__ float dot8(uint4 u, const float* ee) {
    return ((bl(u.x)*ee[0] + bh(u.x)*ee[1]) + (bl(u.y)*ee[2] + bh(u.y)*ee[3]))
         + ((bl(u.z)*ee[4] + bh(u.z)*ee[5]) + (bl(u.w)*ee[6] + bh(u.w)*ee[7]));
}
__device__ __forceinline__ void acc8(uint4 u, float hv, float* ab) {
    ab[0] += bl(u.x)*hv; ab[1] += bh(u.x)*hv; ab[2] += bl(u.y)*hv; ab[3] += bh(u.y)*hv;
    ab[4] += bl(u.z)*hv; ab[5] += bh(u.z)*hv; ab[6] += bl(u.w)*hv; ab[7] += bh(u.w)*hv;
}

// ---------------- zero gn accumulators + init mm ----------------
__global__ void k_zero(float* __restrict__ gnacc, unsigned* __restrict__ mm) {
    int t = threadIdx.x;
    if (t < 256) gnacc[t] = 0.f;
    if (t < 2*BB) mm[t] = (t & 1) ? 0u : 0x7F800000u; // even=min(+inf bits), odd=max(0)
}

// ---- 2x bilinear down (= 2x2 average) + fused GroupNorm partial sums ----
__global__ __launch_bounds__(256) void k_down(const float* __restrict__ x,
                                              float* __restrict__ xd,
                                              float* __restrict__ gnacc) {
    int idx = blockIdx.x * 256 + threadIdx.x;        // B*C*96*96; 36 blocks per channel
    int xw = idx % WD; int t = idx / WD;
    int y = t % HD;   int bc = t / HD;               // uniform per block
    const float* p = x + (size_t)bc * HWSZ + (2*y)*WW + 2*xw;
    float p0 = p[0], p1 = p[1], p2 = p[WW], p3 = p[WW+1];
    xd[idx] = 0.25f*((p0+p2) + (p1+p3));             // H lerp then W lerp == plain avg
    float s  = (p0+p1) + (p2+p3);
    float sq = (p0*p0+p1*p1) + (p2*p2+p3*p3);
    __shared__ float ss[256], sq2[256];
    ss[threadIdx.x] = s; sq2[threadIdx.x] = sq;
    __syncthreads();
    for (int o = 128; o > 0; o >>= 1) {
        if (threadIdx.x < o) {
            ss[threadIdx.x]  += ss[threadIdx.x+o];
            sq2[threadIdx.x] += sq2[threadIdx.x+o];
        }
        __syncthreads();
    }
    if (threadIdx.x == 0) {
        int b = bc >> 6, g = (bc & 63) >> 1;
        atomicAdd(&gnacc[2*(b*GG+g)],   ss[0]);
        atomicAdd(&gnacc[2*(b*GG+g)+1], sq2[0]);
    }
}

// ---------------- finalize GroupNorm stats ----------------
__global__ void k_gn_final(const float* __restrict__ gnacc, float* __restrict__ gn) {
    int t = threadIdx.x;
    if (t < BB*GG) {
        float n = 2.f*HWSZ;
        float mu  = gnacc[2*t] / n;
        float var = gnacc[2*t+1] / n - mu*mu;
        gn[2*t]   = mu;
        gn[2*t+1] = rsqrtf(var + 1e-5f);
    }
}

// ---- df = sum_c |x - up(xd)| using precomputed xd; also ||x||_c ----
// 2 threads per pixel: lanes 0-31 = channels 0-31, lanes 32-63 = channels 32-63.
__global__ __launch_bounds__(256) void k_df(const float* __restrict__ x,
                                            const float* __restrict__ xd,
                                            float* __restrict__ df,
                                            float* __restrict__ nrm,
                                            unsigned* __restrict__ mm) {
    int b = blockIdx.x / BPB;
    int pb = blockIdx.x % BPB;
    int lane = threadIdx.x & 63, wave = threadIdx.x >> 6;
    int half = lane >> 5;
    int p = pb*PBLK + wave*32 + (lane & 31);
    int h = p / WW, w = p % WW;
    float hs = fminf(fmaxf(0.5f*(float)h - 0.25f, 0.f), 95.f);
    float wsr= fminf(fmaxf(0.5f*(float)w - 0.25f, 0.f), 95.f);
    int hl = (int)hs; int hh2 = min(hl+1, 95); float fh = hs - (float)hl;
    int wl = (int)wsr; int wh2 = min(wl+1, 95); float fw = wsr - (float)wl;

    const float* xb = x + (size_t)b*CC*HWSZ;
    const float* db = xd + (size_t)(b*CC + 32*half)*(HD*WD);
    float s = 0.f, sq = 0.f;
    #pragma unroll 4
    for (int cc = 0; cc < 32; ++cc) {
        const float* pc = xb + (size_t)(32*half + cc)*HWSZ;
        float xc = pc[p];
        const float* d = db + cc*(HD*WD);
        float v00 = d[hl*WD+wl],  v01 = d[hl*WD+wh2];
        float v10 = d[hh2*WD+wl], v11 = d[hh2*WD+wh2];
        float t0 = (1.f-fh)*v00 + fh*v10;   // H lerp first
        float t1 = (1.f-fh)*v01 + fh*v11;
        float du = (1.f-fw)*t0 + fw*t1;     // then W
        s  += fabsf(xc - du);
        sq += xc*xc;
    }
    s  += __shfl_xor(s, 32);
    sq += __shfl_xor(sq, 32);
    if (half == 0) {
        df[b*HWSZ+p]  = s;
        nrm[b*HWSZ+p] = sqrtf(sq);
    }

    __shared__ float smin[256], smax[256];
    smin[threadIdx.x] = s; smax[threadIdx.x] = s;
    __syncthreads();
    for (int o = 128; o > 0; o >>= 1) {
        if (threadIdx.x < o) {
            smin[threadIdx.x] = fminf(smin[threadIdx.x], smin[threadIdx.x+o]);
            smax[threadIdx.x] = fmaxf(smax[threadIdx.x], smax[threadIdx.x+o]);
        }
        __syncthreads();
    }
    if (threadIdx.x == 0) {
        atomicMin(&mm[2*b],   __float_as_uint(smin[0]));
        atomicMax(&mm[2*b+1], __float_as_uint(smax[0]));
    }
}

// ---------- fallback (small-ws) versions: GN full pass + df with on-the-fly down ----------
__global__ __launch_bounds__(256) void k_gn_fb(const float* __restrict__ x,
                                               float* __restrict__ gn,
                                               unsigned* __restrict__ mm) {
    if (blockIdx.x == 0 && threadIdx.x < 2*BB)
        mm[threadIdx.x] = (threadIdx.x & 1) ? 0u : 0x7F800000u;
    __shared__ float ss[256], sq2[256];
    int bg = blockIdx.x;
    const float* p = x + (size_t)bg * 2 * HWSZ;
    float s = 0.f, q = 0.f;
    for (int i = threadIdx.x; i < 2*HWSZ; i += 256) { float v = p[i]; s += v; q += v*v; }
    ss[threadIdx.x] = s; sq2[threadIdx.x] = q;
    __syncthreads();
    for (int o = 128; o > 0; o >>= 1) {
        if (threadIdx.x < o) { ss[threadIdx.x] += ss[threadIdx.x+o]; sq2[threadIdx.x] += sq2[threadIdx.x+o]; }
        __syncthreads();
    }
    if (threadIdx.x == 0) {
        float mu  = ss[0]  / (2.f*HWSZ);
        float var = sq2[0] / (2.f*HWSZ) - mu*mu;
        gn[bg*2] = mu; gn[bg*2+1] = rsqrtf(var + 1e-5f);
    }
}
__global__ __launch_bounds__(256) void k_df_fb(const float* __restrict__ x,
                                               float* __restrict__ df,
                                               float* __restrict__ nrm,
                                               unsigned* __restrict__ mm) {
    int b = blockIdx.x / BPB;
    int pb = blockIdx.x % BPB;
    int lane = threadIdx.x & 63, wave = threadIdx.x >> 6;
    int half = lane >> 5;
    int p = pb*PBLK + wave*32 + (lane & 31);
    int h = p / WW, w = p % WW;
    float hs = fminf(fmaxf(0.5f*(float)h - 0.25f, 0.f), 95.f);
    float wsr= fminf(fmaxf(0.5f*(float)w - 0.25f, 0.f), 95.f);
    int hl = (int)hs; int hh2 = min(hl+1, 95); float fh = hs - (float)hl;
    int wl = (int)wsr; int wh2 = min(wl+1, 95); float fw = wsr - (float)wl;
    int r0 = 2*hl, r1 = 2*hh2, q0 = 2*wl, q1 = 2*wh2;
    const float* xb = x + (size_t)b*CC*HWSZ;
    float s = 0.f, sq = 0.f;
    for (int cc = 0; cc < 32; ++cc) {
        const float* pc = xb + (size_t)(32*half + cc)*HWSZ;
        float xc = pc[p];
        const float* a0 = pc + r0*WW;
        const float* a1 = pc + r1*WW;
        float v00 = 0.25f*(a0[q0]+a0[q0+1]+a0[q0+WW]+a0[q0+WW+1]);
        float v01 = 0.25f*(a0[q1]+a0[q1+1]+a0[q1+WW]+a0[q1+WW+1]);
        float v10 = 0.25f*(a1[q0]+a1[q0+1]+a1[q0+WW]+a1[q0+WW+1]);
        float v11 = 0.25f*(a1[q1]+a1[q1+1]+a1[q1+WW]+a1[q1+WW+1]);
        float t0 = (1.f-fh)*v00 + fh*v10;
        float t1 = (1.f-fh)*v01 + fh*v11;
        float du = (1.f-fw)*t0 + fw*t1;
        s  += fabsf(xc - du);
        sq += xc*xc;
    }
    s  += __shfl_xor(s, 32);
    sq += __shfl_xor(sq, 32);
    if (half == 0) { df[b*HWSZ+p] = s; nrm[b*HWSZ+p] = sqrtf(sq); }
    __shared__ float smin[256], smax[256];
    smin[threadIdx.x] = s; smax[threadIdx.x] = s;
    __syncthreads();
    for (int o = 128; o > 0; o >>= 1) {
        if (threadIdx.x < o) {
            smin[threadIdx.x] = fminf(smin[threadIdx.x], smin[threadIdx.x+o]);
            smax[threadIdx.x] = fmaxf(smax[threadIdx.x], smax[threadIdx.x+o]);
        }
        __syncthreads();
    }
    if (threadIdx.x == 0) {
        atomicMin(&mm[2*b],   __float_as_uint(smin[0]));
        atomicMax(&mm[2*b+1], __float_as_uint(smax[0]));
    }
}

// ------- fused: sims + adaptive top-k softmax + GN affine + FFN + residual -------
__global__ __launch_bounds__(256) void k_fused(const float* __restrict__ x,
                                               const float* __restrict__ df,
                                               const float* __restrict__ nrm,
                                               const unsigned* __restrict__ mm,
                                               const float* __restrict__ gn,
                                               const float* __restrict__ gw,
                                               const float* __restrict__ gb,
                                               const float* __restrict__ w1,
                                               const float* __restrict__ b1,
                                               const float* __restrict__ w2,
                                               const float* __restrict__ b2,
                                               float* __restrict__ out) {
    __shared__ __align__(16) unsigned sw1u[128*32]; // uint m: w1[j][2m]|w1[j][2m+1]
    __shared__ __align__(16) unsigned sw2u[128*36]; // ushort rows of 72: [j][c]=w2[c][j]
    __shared__ float sb1[128];
    for (int i = threadIdx.x; i < 4096; i += 256) {
        float2 v = ((const float2*)w1)[i];
        sw1u[i] = (unsigned)f2bf(v.x) | ((unsigned)f2bf(v.y) << 16);
    }
    for (int i = threadIdx.x; i < 8192; i += 256) {
        int c = i >> 7, j = i & 127;
        ((unsigned short*)sw2u)[j*72 + c] = f2bf(w2[i]);
    }
    if (threadIdx.x < 128) sb1[threadIdx.x] = b1[threadIdx.x];

    int b = blockIdx.x / BPB;
    int pb = blockIdx.x % BPB;
    int lane = threadIdx.x & 63, wave = threadIdx.x >> 6;
    int half = lane >> 5;
    int p = pb*PBLK + wave*32 + (lane & 31);
    int h = p / WW, w = p % WW;
    int cbase = 32*half;

    float dmin = __uint_as_float(mm[2*b]);
    float dmax = __uint_as_float(mm[2*b+1]);
    float dfp = (df[b*HWSZ+p] - dmin) / (dmax - dmin + 1e-8f);
    dfp = dfp * dfp;
    bool mask = dfp > 0.3f;
    float conn = 1.f + (mask ? fmaxf(rintf(dfp * 15.f), 0.f) : 0.f);
    bool process = conn > 1.f;
    int kk = (int)fminf(conn, 9.f);

    const float* xb = x + (size_t)b*CC*HWSZ + p;

    const int dh[9] = {-1,-1,-1, 0,0,0, 1,1,1};
    const int dw[9] = {-1, 0, 1,-1,0,1,-1,0,1};
    bool valid[9]; int off[9];
    #pragma unroll
    for (int j = 0; j < 9; ++j) {
        int hn = h + dh[j], wn = w + dw[j];
        valid[j] = (hn >= 0) && (hn < HH) && (wn >= 0) && (wn < WW);
        off[j] = dh[j]*WW + dw[j];
    }

    float wt[9];
    #pragma unroll
    for (int j = 0; j < 9; ++j) wt[j] = 0.f;

    if (process) {
        float dot[9];
        #pragma unroll
        for (int j = 0; j < 9; ++j) dot[j] = 0.f;
        for (int cc = 0; cc < 32; ++cc) {
            const float* pc = xb + (size_t)(cbase + cc)*HWSZ;
            float xc = pc[0];
            #pragma unroll
            for (int j = 0; j < 9; ++j)
                if (valid[j]) dot[j] += xc * pc[off[j]];
        }
        #pragma unroll
        for (int j = 0; j < 9; ++j)
            dot[j] += __shfl_xor(dot[j], 32);   // partner shares `process`
        float nc = fmaxf(nrm[b*HWSZ+p], 1e-12f);
        float sim[9];
        #pragma unroll
        for (int j = 0; j < 9; ++j) {
            if (valid[j]) {
                float nj = fmaxf(nrm[b*HWSZ+p+off[j]], 1e-12f);
                sim[j] = dot[j] / (nc * nj);
            } else sim[j] = 0.f;   // zero-pad patch => exact 0; index tie-break below
        }
        float S = 0.f;
        #pragma unroll
        for (int j = 0; j < 9; ++j) {
            int rank = 0;
            #pragma unroll
            for (int l = 0; l < 9; ++l)
                rank += (sim[l] > sim[j]) || (sim[l] == sim[j] && l < j);
            float e = (rank < kk) ? expf(sim[j]) : 0.f;   // stable top-k == argsort(-sim)
            wt[j] = e; S += e;
        }
        float inv = 1.f / fmaxf(S, 1e-12f);
        #pragma unroll
        for (int j = 0; j < 9; ++j) wt[j] *= inv;
    }

    // ---- enhanced = weighted/identity + GN affine, own 32 channels in registers ----
    float e[32];
    for (int cc = 0; cc < 32; ++cc) {
        int c = cbase + cc;
        const float* pc = xb + (size_t)c*HWSZ;
        float xc = pc[0];
        float oc;
        if (process) {
            float a = 0.f;
            #pragma unroll
            for (int j = 0; j < 9; ++j)
                if (valid[j]) a += wt[j] * pc[off[j]];
            oc = a;
        } else {
            oc = xc;
        }
        int g = c >> 1;
        float mu = gn[(b*GG+g)*2], is = gn[(b*GG+g)*2+1];
        e[cc] = oc + (xc - mu) * is * gw[c] + gb[c];
    }

    __syncthreads();   // LDS weights ready

    // ---- FFN: out = e + w2 @ relu(w1 @ e + b1) + b2 ----
    // 2-way j unroll + tree-structured dot8 partials to break serial FMA chains.
    float acc[32];
    #pragma unroll
    for (int cc = 0; cc < 32; ++cc) acc[cc] = e[cc] + b2[cbase + cc];
    for (int j = 0; j < 128; j += 2) {
        const uint4* r1a = (const uint4*)&sw1u[ j   *32 + 16*half];
        const uint4* r1b = (const uint4*)&sw1u[(j+1)*32 + 16*half];
        uint4 a0=r1a[0], a1=r1a[1], a2=r1a[2], a3=r1a[3];
        uint4 c0=r1b[0], c1=r1b[1], c2=r1b[2], c3=r1b[3];
        float ha = (dot8(a0,e) + dot8(a1,e+8)) + (dot8(a2,e+16) + dot8(a3,e+24));
        float hb = (dot8(c0,e) + dot8(c1,e+8)) + (dot8(c2,e+16) + dot8(c3,e+24));
        ha += __shfl_xor(ha, 32);
        hb += __shfl_xor(hb, 32);
        ha = fmaxf(ha + sb1[j],   0.f);
        hb = fmaxf(hb + sb1[j+1], 0.f);
        const uint4* r2a = (const uint4*)&sw2u[ j   *36 + 16*half];
        const uint4* r2b = (const uint4*)&sw2u[(j+1)*36 + 16*half];
        uint4 d0=r2a[0], d1=r2a[1], d2=r2a[2], d3=r2a[3];
        uint4 f0=r2b[0], f1=r2b[1], f2=r2b[2], f3=r2b[3];
        acc8(d0, ha, acc); acc8(d1, ha, acc+8); acc8(d2, ha, acc+16); acc8(d3, ha, acc+24);
        acc8(f0, hb, acc); acc8(f1, hb, acc+8); acc8(f2, hb, acc+16); acc8(f3, hb, acc+24);
    }
    float* ob = out + (size_t)b*CC*HWSZ + (size_t)cbase*HWSZ + p;
    #pragma unroll
    for (int cc = 0; cc < 32; ++cc) ob[(size_t)cc*HWSZ] = acc[cc];
}

extern "C" void kernel_launch(void* const* d_in, const int* in_sizes, int n_in,
                              void* d_out, int out_size, void* d_ws, size_t ws_size,
                              hipStream_t stream) {
    const float* x  = (const float*)d_in[0];
    const float* gw = (const float*)d_in[1];
    const float* gb = (const float*)d_in[2];
    const float* w1 = (const float*)d_in[3];
    const float* b1 = (const float*)d_in[4];
    const float* w2 = (const float*)d_in[5];
    const float* b2 = (const float*)d_in[6];
    float* out = (float*)d_out;

    // big ws layout (floats): xd 2359296 | df 147456 | nrm 147456 | gnacc 256 | gn 256 | mm 8u
    const size_t NEED = (size_t)(2359296 + 147456 + 147456 + 256 + 256 + 8) * 4;
    float* ws = (float*)d_ws;
    if (ws_size >= NEED) {
        float* xd    = ws;
        float* df    = xd + 2359296;
        float* nrm   = df + 147456;
        float* gnacc = nrm + 147456;
        float* gn    = gnacc + 256;
        unsigned* mm = (unsigned*)(gn + 256);
        k_zero    <<<1, 256, 0, stream>>>(gnacc, mm);
        k_down    <<<(BB*CC*HD*WD)/256, 256, 0, stream>>>(x, xd, gnacc);
        k_gn_final<<<1, 128, 0, stream>>>(gnacc, gn);
        k_df      <<<BB*BPB, 256, 0, stream>>>(x, xd, df, nrm, mm);
        k_fused   <<<BB*BPB, 256, 0, stream>>>(x, df, nrm, mm, gn, gw, gb,
                                               w1, b1, w2, b2, out);
    } else {
        // small fallback: df 147456 | nrm 147456 | gn 256 | mm 8u (~1.18 MB)
        float* df    = ws;
        float* nrm   = df + 147456;
        float* gn    = nrm + 147456;
        unsigned* mm = (unsigned*)(gn + 256);
        k_gn_fb<<<BB*GG, 256, 0, stream>>>(x, gn, mm);
        k_df_fb<<<BB*BPB, 256, 0, stream>>>(x, df, nrm, mm);
        k_fused<<<BB*BPB, 256, 0, stream>>>(x, df, nrm, mm, gn, gw, gb,
                                            w1, b1, w2, b2, out);
    }
}

// Round 7
// 452.262 us; speedup vs baseline: 2.5393x; 1.1685x over previous
//
#include <hip/hip_runtime.h>
#include <hip/hip_bf16.h>

#define BB 4
#define CC 64
#define HH 192
#define WW 192
#define HWSZ (HH*WW)          // 36864
#define HD 96
#define WD 96
#define GG 32
// fused kernel geometry: 512 threads, 256 pixels (2 threads/pixel in phase 1)
#define FTH 512
#define FPX 256
#define FBPB (HWSZ/FPX)       // 144 blocks per batch
// df kernel geometry: 256 threads, 128 pixels
#define PBLK 128
#define BPB (HWSZ/PBLK)       // 288 blocks per batch

typedef short short8 __attribute__((ext_vector_type(8)));
typedef float f32x4  __attribute__((ext_vector_type(4)));

__device__ __forceinline__ unsigned short f2bf(float f) {
    unsigned u = __float_as_uint(f);
    return (unsigned short)((u + 0x7FFFu + ((u >> 16) & 1u)) >> 16);
}
__device__ __forceinline__ float bf2f(unsigned short s) {
    return __uint_as_float(((unsigned)s) << 16);
}
__device__ __forceinline__ unsigned pk2(float a, float b) {
    return (unsigned)f2bf(a) | ((unsigned)f2bf(b) << 16);
}
__device__ __forceinline__ short8 u4s8(uint4 u) {
    union { uint4 a; short8 b; } cvt; cvt.a = u; return cvt.b;
}

// ---------------- zero gn accumulators + init mm ----------------
__global__ void k_zero(float* __restrict__ gnacc, unsigned* __restrict__ mm) {
    int t = threadIdx.x;
    if (t < 256) gnacc[t] = 0.f;
    if (t < 2*BB) mm[t] = (t & 1) ? 0u : 0x7F800000u; // even=min(+inf bits), odd=max(0)
}

// ---- 2x bilinear down (= 2x2 average) + fused GroupNorm partial sums ----
__global__ __launch_bounds__(256) void k_down(const float* __restrict__ x,
                                              float* __restrict__ xd,
                                              float* __restrict__ gnacc) {
    int idx = blockIdx.x * 256 + threadIdx.x;        // B*C*96*96
    int xw = idx % WD; int t = idx / WD;
    int y = t % HD;   int bc = t / HD;               // uniform per block
    const float* p = x + (size_t)bc * HWSZ + (2*y)*WW + 2*xw;
    float p0 = p[0], p1 = p[1], p2 = p[WW], p3 = p[WW+1];
    xd[idx] = 0.25f*((p0+p2) + (p1+p3));
    float s  = (p0+p1) + (p2+p3);
    float sq = (p0*p0+p1*p1) + (p2*p2+p3*p3);
    __shared__ float ss[256], sq2[256];
    ss[threadIdx.x] = s; sq2[threadIdx.x] = sq;
    __syncthreads();
    for (int o = 128; o > 0; o >>= 1) {
        if (threadIdx.x < o) {
            ss[threadIdx.x]  += ss[threadIdx.x+o];
            sq2[threadIdx.x] += sq2[threadIdx.x+o];
        }
        __syncthreads();
    }
    if (threadIdx.x == 0) {
        int b = bc >> 6, g = (bc & 63) >> 1;
        atomicAdd(&gnacc[2*(b*GG+g)],   ss[0]);
        atomicAdd(&gnacc[2*(b*GG+g)+1], sq2[0]);
    }
}

// ---------------- finalize GroupNorm stats ----------------
__global__ void k_gn_final(const float* __restrict__ gnacc, float* __restrict__ gn) {
    int t = threadIdx.x;
    if (t < BB*GG) {
        float n = 2.f*HWSZ;
        float mu  = gnacc[2*t] / n;
        float var = gnacc[2*t+1] / n - mu*mu;
        gn[2*t]   = mu;
        gn[2*t+1] = rsqrtf(var + 1e-5f);
    }
}

// ---- df = sum_c |x - up(xd)| using precomputed xd; also ||x||_c ----
__global__ __launch_bounds__(256) void k_df(const float* __restrict__ x,
                                            const float* __restrict__ xd,
                                            float* __restrict__ df,
                                            float* __restrict__ nrm,
                                            unsigned* __restrict__ mm) {
    int b = blockIdx.x / BPB;
    int pb = blockIdx.x % BPB;
    int lane = threadIdx.x & 63, wave = threadIdx.x >> 6;
    int half = lane >> 5;
    int p = pb*PBLK + wave*32 + (lane & 31);
    int h = p / WW, w = p % WW;
    float hs = fminf(fmaxf(0.5f*(float)h - 0.25f, 0.f), 95.f);
    float wsr= fminf(fmaxf(0.5f*(float)w - 0.25f, 0.f), 95.f);
    int hl = (int)hs; int hh2 = min(hl+1, 95); float fh = hs - (float)hl;
    int wl = (int)wsr; int wh2 = min(wl+1, 95); float fw = wsr - (float)wl;

    const float* xb = x + (size_t)b*CC*HWSZ;
    const float* db = xd + (size_t)(b*CC + 32*half)*(HD*WD);
    float s = 0.f, sq = 0.f;
    #pragma unroll 4
    for (int cc = 0; cc < 32; ++cc) {
        const float* pc = xb + (size_t)(32*half + cc)*HWSZ;
        float xc = pc[p];
        const float* d = db + cc*(HD*WD);
        float v00 = d[hl*WD+wl],  v01 = d[hl*WD+wh2];
        float v10 = d[hh2*WD+wl], v11 = d[hh2*WD+wh2];
        float t0 = (1.f-fh)*v00 + fh*v10;
        float t1 = (1.f-fh)*v01 + fh*v11;
        float du = (1.f-fw)*t0 + fw*t1;
        s  += fabsf(xc - du);
        sq += xc*xc;
    }
    s  += __shfl_xor(s, 32);
    sq += __shfl_xor(sq, 32);
    if (half == 0) {
        df[b*HWSZ+p]  = s;
        nrm[b*HWSZ+p] = sqrtf(sq);
    }
    __shared__ float smin[256], smax[256];
    smin[threadIdx.x] = s; smax[threadIdx.x] = s;
    __syncthreads();
    for (int o = 128; o > 0; o >>= 1) {
        if (threadIdx.x < o) {
            smin[threadIdx.x] = fminf(smin[threadIdx.x], smin[threadIdx.x+o]);
            smax[threadIdx.x] = fmaxf(smax[threadIdx.x], smax[threadIdx.x+o]);
        }
        __syncthreads();
    }
    if (threadIdx.x == 0) {
        atomicMin(&mm[2*b],   __float_as_uint(smin[0]));
        atomicMax(&mm[2*b+1], __float_as_uint(smax[0]));
    }
}

// ---------- fallback (small-ws): GN full pass + df with on-the-fly down ----------
__global__ __launch_bounds__(256) void k_gn_fb(const float* __restrict__ x,
                                               float* __restrict__ gn,
                                               unsigned* __restrict__ mm) {
    if (blockIdx.x == 0 && threadIdx.x < 2*BB)
        mm[threadIdx.x] = (threadIdx.x & 1) ? 0u : 0x7F800000u;
    __shared__ float ss[256], sq2[256];
    int bg = blockIdx.x;
    const float* p = x + (size_t)bg * 2 * HWSZ;
    float s = 0.f, q = 0.f;
    for (int i = threadIdx.x; i < 2*HWSZ; i += 256) { float v = p[i]; s += v; q += v*v; }
    ss[threadIdx.x] = s; sq2[threadIdx.x] = q;
    __syncthreads();
    for (int o = 128; o > 0; o >>= 1) {
        if (threadIdx.x < o) { ss[threadIdx.x] += ss[threadIdx.x+o]; sq2[threadIdx.x] += sq2[threadIdx.x+o]; }
        __syncthreads();
    }
    if (threadIdx.x == 0) {
        float mu  = ss[0]  / (2.f*HWSZ);
        float var = sq2[0] / (2.f*HWSZ) - mu*mu;
        gn[bg*2] = mu; gn[bg*2+1] = rsqrtf(var + 1e-5f);
    }
}
__global__ __launch_bounds__(256) void k_df_fb(const float* __restrict__ x,
                                               float* __restrict__ df,
                                               float* __restrict__ nrm,
                                               unsigned* __restrict__ mm) {
    int b = blockIdx.x / BPB;
    int pb = blockIdx.x % BPB;
    int lane = threadIdx.x & 63, wave = threadIdx.x >> 6;
    int half = lane >> 5;
    int p = pb*PBLK + wave*32 + (lane & 31);
    int h = p / WW, w = p % WW;
    float hs = fminf(fmaxf(0.5f*(float)h - 0.25f, 0.f), 95.f);
    float wsr= fminf(fmaxf(0.5f*(float)w - 0.25f, 0.f), 95.f);
    int hl = (int)hs; int hh2 = min(hl+1, 95); float fh = hs - (float)hl;
    int wl = (int)wsr; int wh2 = min(wl+1, 95); float fw = wsr - (float)wl;
    int r0 = 2*hl, r1 = 2*hh2, q0 = 2*wl, q1 = 2*wh2;
    const float* xb = x + (size_t)b*CC*HWSZ;
    float s = 0.f, sq = 0.f;
    for (int cc = 0; cc < 32; ++cc) {
        const float* pc = xb + (size_t)(32*half + cc)*HWSZ;
        float xc = pc[p];
        const float* a0 = pc + r0*WW;
        const float* a1 = pc + r1*WW;
        float v00 = 0.25f*(a0[q0]+a0[q0+1]+a0[q0+WW]+a0[q0+WW+1]);
        float v01 = 0.25f*(a0[q1]+a0[q1+1]+a0[q1+WW]+a0[q1+WW+1]);
        float v10 = 0.25f*(a1[q0]+a1[q0+1]+a1[q0+WW]+a1[q0+WW+1]);
        float v11 = 0.25f*(a1[q1]+a1[q1+1]+a1[q1+WW]+a1[q1+WW+1]);
        float t0 = (1.f-fh)*v00 + fh*v10;
        float t1 = (1.f-fh)*v01 + fh*v11;
        float du = (1.f-fw)*t0 + fw*t1;
        s  += fabsf(xc - du);
        sq += xc*xc;
    }
    s  += __shfl_xor(s, 32);
    sq += __shfl_xor(sq, 32);
    if (half == 0) { df[b*HWSZ+p] = s; nrm[b*HWSZ+p] = sqrtf(sq); }
    __shared__ float smin[256], smax[256];
    smin[threadIdx.x] = s; smax[threadIdx.x] = s;
    __syncthreads();
    for (int o = 128; o > 0; o >>= 1) {
        if (threadIdx.x < o) {
            smin[threadIdx.x] = fminf(smin[threadIdx.x], smin[threadIdx.x+o]);
            smax[threadIdx.x] = fmaxf(smax[threadIdx.x], smax[threadIdx.x+o]);
        }
        __syncthreads();
    }
    if (threadIdx.x == 0) {
        atomicMin(&mm[2*b],   __float_as_uint(smin[0]));
        atomicMax(&mm[2*b+1], __float_as_uint(smax[0]));
    }
}

// ------- fused: sims + top-k softmax + GN affine (phase 1) + MFMA FFN (phase 2) -------
// LDS frag-packed layouts (frag = 64 lanes x 16 B):
//   sw1: B-frags of w1  [frag = nt*2+kc]          16 KB
//   sw2: B-frags of w2  [frag = kc2*4+nt2]        16 KB
//   se : A-frags of e   [frag = tt*2+kc]          32 KB  (also residual source)
//   sh : per-wave A'-frag scratch (1 KB each)      8 KB
__global__ __launch_bounds__(FTH, 4) void k_fused(const float* __restrict__ x,
                                                  const float* __restrict__ df,
                                                  const float* __restrict__ nrm,
                                                  const unsigned* __restrict__ mm,
                                                  const float* __restrict__ gn,
                                                  const float* __restrict__ gw,
                                                  const float* __restrict__ gb,
                                                  const float* __restrict__ w1,
                                                  const float* __restrict__ b1,
                                                  const float* __restrict__ w2,
                                                  const float* __restrict__ b2,
                                                  float* __restrict__ out) {
    __shared__ __align__(16) unsigned char lds[73728];
    unsigned* sw1 = (unsigned*)lds;                 // 4096 uints
    unsigned* sw2 = (unsigned*)(lds + 16384);       // 4096 uints
    unsigned* se  = (unsigned*)(lds + 32768);       // 8192 uints
    unsigned* sh  = (unsigned*)(lds + 65536);       // 2048 uints

    int tid = threadIdx.x;
    // ---- stage w1 into B-frag order: element (j,c) -> frag=(j>>4)*2+(c>>5),
    //      lane=((c&31)>>3)*16+(j&15), word=(c&7)/2
    for (int i = tid; i < 4096; i += FTH) {
        float2 v = ((const float2*)w1)[i];          // j = i>>5, c0 = (i&31)*2
        int j = i >> 5, cp = i & 31, c0 = cp << 1;
        int fi = ((j >> 4) << 1) + (c0 >> 5);
        int ln = (((c0 & 31) >> 3) << 4) + (j & 15);
        sw1[fi*256 + ln*4 + (cp & 3)] = pk2(v.x, v.y);
    }
    // ---- stage w2 into B-frag order: element (c,j) -> frag=(j>>5)*4+(c>>4),
    //      lane=((j&31)>>3)*16+(c&15), word=(j&7)/2
    for (int i = tid; i < 4096; i += FTH) {
        float2 v = ((const float2*)w2)[i];          // c = i>>6, j0 = (i&63)*2
        int c = i >> 6, jp = i & 63, j0 = jp << 1;
        int fi = ((j0 >> 5) << 2) + (c >> 4);
        int ln = (((j0 & 31) >> 3) << 4) + (c & 15);
        sw2[fi*256 + ln*4 + (jp & 3)] = pk2(v.x, v.y);
    }

    // ================= phase 1: sims + top-k softmax + GN affine =================
    int wv = tid >> 6, lane = tid & 63;
    int half = lane >> 5;
    int pxl = wv*32 + (lane & 31);                  // 0..255 local pixel
    int blk = blockIdx.x;
    int b = blk / FBPB;
    int pb = (blk % FBPB) * FPX;
    int p = pb + pxl;
    int h = p / WW, w = p % WW;
    int cbase = 32*half;

    float dmin = __uint_as_float(mm[2*b]);
    float dmax = __uint_as_float(mm[2*b+1]);
    float dfp = (df[b*HWSZ+p] - dmin) / (dmax - dmin + 1e-8f);
    dfp = dfp * dfp;
    bool maskv = dfp > 0.3f;
    float conn = 1.f + (maskv ? fmaxf(rintf(dfp * 15.f), 0.f) : 0.f);
    bool process = conn > 1.f;
    int kk = (int)fminf(conn, 9.f);

    const float* xb = x + (size_t)b*CC*HWSZ + p;
    const int dh[9] = {-1,-1,-1, 0,0,0, 1,1,1};
    const int dwv[9] = {-1, 0, 1,-1,0,1,-1,0,1};
    bool valid[9]; int off[9];
    #pragma unroll
    for (int j = 0; j < 9; ++j) {
        int hn = h + dh[j], wn = w + dwv[j];
        valid[j] = (hn >= 0) && (hn < HH) && (wn >= 0) && (wn < WW);
        off[j] = dh[j]*WW + dwv[j];
    }
    float wt[9];
    #pragma unroll
    for (int j = 0; j < 9; ++j) wt[j] = 0.f;

    if (process) {
        float dot[9];
        #pragma unroll
        for (int j = 0; j < 9; ++j) dot[j] = 0.f;
        for (int cc = 0; cc < 32; ++cc) {
            const float* pc = xb + (size_t)(cbase + cc)*HWSZ;
            float xc = pc[0];
            #pragma unroll
            for (int j = 0; j < 9; ++j)
                if (valid[j]) dot[j] += xc * pc[off[j]];
        }
        #pragma unroll
        for (int j = 0; j < 9; ++j)
            dot[j] += __shfl_xor(dot[j], 32);       // partner shares `process`
        float nc = fmaxf(nrm[b*HWSZ+p], 1e-12f);
        float sim[9];
        #pragma unroll
        for (int j = 0; j < 9; ++j) {
            if (valid[j]) {
                float nj = fmaxf(nrm[b*HWSZ+p+off[j]], 1e-12f);
                sim[j] = dot[j] / (nc * nj);
            } else sim[j] = 0.f;                    // zero-pad => exact 0; index tiebreak
        }
        float S = 0.f;
        #pragma unroll
        for (int j = 0; j < 9; ++j) {
            int rank = 0;
            #pragma unroll
            for (int l = 0; l < 9; ++l)
                rank += (sim[l] > sim[j]) || (sim[l] == sim[j] && l < j);
            float ex = (rank < kk) ? expf(sim[j]) : 0.f;  // == stable argsort(-sim)
            wt[j] = ex; S += ex;
        }
        float inv = 1.f / fmaxf(S, 1e-12f);
        #pragma unroll
        for (int j = 0; j < 9; ++j) wt[j] *= inv;
    }

    float e[32];
    for (int cc = 0; cc < 32; ++cc) {
        int c = cbase + cc;
        const float* pc = xb + (size_t)c*HWSZ;
        float xc = pc[0];
        float oc;
        if (process) {
            float a = 0.f;
            #pragma unroll
            for (int j = 0; j < 9; ++j)
                if (valid[j]) a += wt[j] * pc[off[j]];
            oc = a;
        } else oc = xc;
        int g = c >> 1;
        float mu = gn[(b*GG+g)*2], is = gn[(b*GG+g)*2+1];
        e[cc] = oc + (xc - mu) * is * gw[c] + gb[c];
    }

    // write e into A-frag order: pixel pxl (tt=pxl>>4, m=pxl&15), ch chunk kc=half
    {
        int tt = pxl >> 4, m = pxl & 15;
        unsigned* dst = se + ((tt*2 + half)*256) + m*4;
        #pragma unroll
        for (int q = 0; q < 4; ++q) {
            uint4 u;
            u.x = pk2(e[q*8+0], e[q*8+1]);
            u.y = pk2(e[q*8+2], e[q*8+3]);
            u.z = pk2(e[q*8+4], e[q*8+5]);
            u.w = pk2(e[q*8+6], e[q*8+7]);
            *(uint4*)(dst + q*64) = u;              // lane q*16+m of the frag
        }
    }
    __syncthreads();

    // ================= phase 2: MFMA FFN =================
    int qd = lane >> 4, n16 = lane & 15;
    float b1v[8], b2v[4];
    #pragma unroll
    for (int nt = 0; nt < 8; ++nt) b1v[nt] = b1[nt*16 + n16];
    #pragma unroll
    for (int n2 = 0; n2 < 4; ++n2) b2v[n2] = b2[n2*16 + n16];

    unsigned short* shw = (unsigned short*)(sh + wv*256);  // this wave's 1 KB scratch
    float* outb = out + (size_t)b*CC*HWSZ;

    for (int t = 0; t < 2; ++t) {
        int ttg = wv*2 + t;                         // tile of 16 pixels
        uint4 a0 = *(uint4*)(se + ((ttg*2+0)*256) + lane*4);
        uint4 a1 = *(uint4*)(se + ((ttg*2+1)*256) + lane*4);
        f32x4 D1[8];
        #pragma unroll
        for (int nt = 0; nt < 8; ++nt) D1[nt] = (f32x4){0.f,0.f,0.f,0.f};
        #pragma unroll
        for (int nt = 0; nt < 8; ++nt) {
            uint4 bk0 = *(uint4*)(sw1 + ((nt*2+0)*256) + lane*4);
            uint4 bk1 = *(uint4*)(sw1 + ((nt*2+1)*256) + lane*4);
            D1[nt] = __builtin_amdgcn_mfma_f32_16x16x32_bf16(u4s8(a0), u4s8(bk0), D1[nt], 0, 0, 0);
            D1[nt] = __builtin_amdgcn_mfma_f32_16x16x32_bf16(u4s8(a1), u4s8(bk1), D1[nt], 0, 0, 0);
        }
        f32x4 D2[4];
        #pragma unroll
        for (int n2 = 0; n2 < 4; ++n2) D2[n2] = (f32x4){0.f,0.f,0.f,0.f};
        for (int kc2 = 0; kc2 < 4; ++kc2) {
            // relu(h) chunk (hidden kc2*32..+31) -> wave scratch in A'-frag order
            #pragma unroll
            for (int h2 = 0; h2 < 2; ++h2) {
                int nt = kc2*2 + h2;
                #pragma unroll
                for (int r = 0; r < 4; ++r) {
                    float hval = fmaxf(D1[nt][r] + b1v[nt], 0.f);
                    int mrow = qd*4 + r;            // pixel row in tile
                    int k = h2*16 + n16;            // hid within 32-chunk
                    shw[((k >> 3)*16 + mrow)*8 + (k & 7)] = f2bf(hval);
                }
            }
            uint4 ah = *(uint4*)(sh + wv*256 + lane*4);   // same-wave LDS RAW: in-order
            #pragma unroll
            for (int n2 = 0; n2 < 4; ++n2) {
                uint4 bb = *(uint4*)(sw2 + ((kc2*4 + n2)*256) + lane*4);
                D2[n2] = __builtin_amdgcn_mfma_f32_16x16x32_bf16(u4s8(ah), u4s8(bb), D2[n2], 0, 0, 0);
            }
        }
        // epilogue: out = D2 + residual(e) + b2
        unsigned short* seu = (unsigned short*)se;
        #pragma unroll
        for (int n2 = 0; n2 < 4; ++n2) {
            int c = n2*16 + n16;
            int kc = c >> 5, qq = (c & 31) >> 3, jj = c & 7;
            float* op = outb + (size_t)c*HWSZ + (pb + ttg*16);
            #pragma unroll
            for (int r = 0; r < 4; ++r) {
                int pxt = qd*4 + r;
                float resid = bf2f(seu[(((ttg*2+kc)*64 + qq*16 + pxt))*8 + jj]);
                op[pxt] = D2[n2][r] + resid + b2v[n2];
            }
        }
    }
}

extern "C" void kernel_launch(void* const* d_in, const int* in_sizes, int n_in,
                              void* d_out, int out_size, void* d_ws, size_t ws_size,
                              hipStream_t stream) {
    const float* x  = (const float*)d_in[0];
    const float* gw = (const float*)d_in[1];
    const float* gb = (const float*)d_in[2];
    const float* w1 = (const float*)d_in[3];
    const float* b1 = (const float*)d_in[4];
    const float* w2 = (const float*)d_in[5];
    const float* b2 = (const float*)d_in[6];
    float* out = (float*)d_out;

    const size_t NEED = (size_t)(2359296 + 147456 + 147456 + 256 + 256 + 8) * 4;
    float* ws = (float*)d_ws;
    if (ws_size >= NEED) {
        float* xd    = ws;
        float* df    = xd + 2359296;
        float* nrm   = df + 147456;
        float* gnacc = nrm + 147456;
        float* gn    = gnacc + 256;
        unsigned* mm = (unsigned*)(gn + 256);
        k_zero    <<<1, 256, 0, stream>>>(gnacc, mm);
        k_down    <<<(BB*CC*HD*WD)/256, 256, 0, stream>>>(x, xd, gnacc);
        k_gn_final<<<1, 128, 0, stream>>>(gnacc, gn);
        k_df      <<<BB*BPB, 256, 0, stream>>>(x, xd, df, nrm, mm);
        k_fused   <<<BB*FBPB, FTH, 0, stream>>>(x, df, nrm, mm, gn, gw, gb,
                                                w1, b1, w2, b2, out);
    } else {
        float* df    = ws;
        float* nrm   = df + 147456;
        float* gn    = nrm + 147456;
        unsigned* mm = (unsigned*)(gn + 256);
        k_gn_fb<<<BB*GG, 256, 0, stream>>>(x, gn, mm);
        k_df_fb<<<BB*BPB, 256, 0, stream>>>(x, df, nrm, mm);
        k_fused<<<BB*FBPB, FTH, 0, stream>>>(x, df, nrm, mm, gn, gw, gb,
                                             w1, b1, w2, b2, out);
    }
}

// Round 8
// 359.536 us; speedup vs baseline: 3.1942x; 1.2579x over previous
//
#include <hip/hip_runtime.h>
#include <hip/hip_bf16.h>

#define BB 4
#define CC 64
#define HH 192
#define WW 192
#define HWSZ (HH*WW)          // 36864
#define HD 96
#define WD 96
#define GG 32
// fused kernel geometry: 512 threads, 256 pixels (2 threads/pixel in phase 1)
#define FTH 512
#define FPX 256
#define FBPB (HWSZ/FPX)       // 144 blocks per batch
// df kernel geometry: 256 threads, 128 pixels
#define PBLK 128
#define BPB (HWSZ/PBLK)       // 288 blocks per batch

typedef short short8 __attribute__((ext_vector_type(8)));
typedef float f32x4  __attribute__((ext_vector_type(4)));

__device__ __forceinline__ unsigned short f2bf(float f) {
    unsigned u = __float_as_uint(f);
    return (unsigned short)((u + 0x7FFFu + ((u >> 16) & 1u)) >> 16);
}
__device__ __forceinline__ float bf2f(unsigned short s) {
    return __uint_as_float(((unsigned)s) << 16);
}
__device__ __forceinline__ unsigned pk2(float a, float b) {
    return (unsigned)f2bf(a) | ((unsigned)f2bf(b) << 16);
}
__device__ __forceinline__ short8 u4s8(uint4 u) {
    union { uint4 a; short8 b; } cvt; cvt.a = u; return cvt.b;
}

// ---------------- zero gn accumulators + init mm ----------------
__global__ void k_zero(float* __restrict__ gnacc, unsigned* __restrict__ mm) {
    int t = threadIdx.x;
    if (t < 256) gnacc[t] = 0.f;
    if (t < 2*BB) mm[t] = (t & 1) ? 0u : 0x7F800000u; // even=min(+inf bits), odd=max(0)
}

// ---- 2x bilinear down (= 2x2 average) + fused GroupNorm partial sums ----
__global__ __launch_bounds__(256) void k_down(const float* __restrict__ x,
                                              float* __restrict__ xd,
                                              float* __restrict__ gnacc) {
    int idx = blockIdx.x * 256 + threadIdx.x;        // B*C*96*96
    int xw = idx % WD; int t = idx / WD;
    int y = t % HD;   int bc = t / HD;               // uniform per block
    const float* p = x + (size_t)bc * HWSZ + (2*y)*WW + 2*xw;
    float p0 = p[0], p1 = p[1], p2 = p[WW], p3 = p[WW+1];
    xd[idx] = 0.25f*((p0+p2) + (p1+p3));
    float s  = (p0+p1) + (p2+p3);
    float sq = (p0*p0+p1*p1) + (p2*p2+p3*p3);
    __shared__ float ss[256], sq2[256];
    ss[threadIdx.x] = s; sq2[threadIdx.x] = sq;
    __syncthreads();
    for (int o = 128; o > 0; o >>= 1) {
        if (threadIdx.x < o) {
            ss[threadIdx.x]  += ss[threadIdx.x+o];
            sq2[threadIdx.x] += sq2[threadIdx.x+o];
        }
        __syncthreads();
    }
    if (threadIdx.x == 0) {
        int b = bc >> 6, g = (bc & 63) >> 1;
        atomicAdd(&gnacc[2*(b*GG+g)],   ss[0]);
        atomicAdd(&gnacc[2*(b*GG+g)+1], sq2[0]);
    }
}

// ---------------- finalize GroupNorm stats ----------------
__global__ void k_gn_final(const float* __restrict__ gnacc, float* __restrict__ gn) {
    int t = threadIdx.x;
    if (t < BB*GG) {
        float n = 2.f*HWSZ;
        float mu  = gnacc[2*t] / n;
        float var = gnacc[2*t+1] / n - mu*mu;
        gn[2*t]   = mu;
        gn[2*t+1] = rsqrtf(var + 1e-5f);
    }
}

// ---- df = sum_c |x - up(xd)| using precomputed xd; also ||x||_c ----
__global__ __launch_bounds__(256) void k_df(const float* __restrict__ x,
                                            const float* __restrict__ xd,
                                            float* __restrict__ df,
                                            float* __restrict__ nrm,
                                            unsigned* __restrict__ mm) {
    int b = blockIdx.x / BPB;
    int pb = blockIdx.x % BPB;
    int lane = threadIdx.x & 63, wave = threadIdx.x >> 6;
    int half = lane >> 5;
    int p = pb*PBLK + wave*32 + (lane & 31);
    int h = p / WW, w = p % WW;
    float hs = fminf(fmaxf(0.5f*(float)h - 0.25f, 0.f), 95.f);
    float wsr= fminf(fmaxf(0.5f*(float)w - 0.25f, 0.f), 95.f);
    int hl = (int)hs; int hh2 = min(hl+1, 95); float fh = hs - (float)hl;
    int wl = (int)wsr; int wh2 = min(wl+1, 95); float fw = wsr - (float)wl;
    bool pair = (wh2 == wl + 1);                   // float2-loadable (all but last col)

    const float* xb = x + (size_t)b*CC*HWSZ;
    const float* db = xd + (size_t)(b*CC + 32*half)*(HD*WD);
    float s = 0.f, sq = 0.f;
    #pragma unroll 4
    for (int cc = 0; cc < 32; ++cc) {
        const float* pc = xb + (size_t)(32*half + cc)*HWSZ;
        float xc = pc[p];
        const float* d = db + cc*(HD*WD);
        float v00, v01, v10, v11;
        if (pair) {
            float2 a = *(const float2*)(d + hl*WD + wl);
            float2 bqq = *(const float2*)(d + hh2*WD + wl);
            v00 = a.x; v01 = a.y; v10 = bqq.x; v11 = bqq.y;
        } else {
            v00 = d[hl*WD+wl];  v01 = d[hl*WD+wh2];
            v10 = d[hh2*WD+wl]; v11 = d[hh2*WD+wh2];
        }
        float t0 = (1.f-fh)*v00 + fh*v10;
        float t1 = (1.f-fh)*v01 + fh*v11;
        float du = (1.f-fw)*t0 + fw*t1;
        s  += fabsf(xc - du);
        sq += xc*xc;
    }
    s  += __shfl_xor(s, 32);
    sq += __shfl_xor(sq, 32);
    if (half == 0) {
        df[b*HWSZ+p]  = s;
        nrm[b*HWSZ+p] = sqrtf(sq);
    }
    __shared__ float smin[256], smax[256];
    smin[threadIdx.x] = s; smax[threadIdx.x] = s;
    __syncthreads();
    for (int o = 128; o > 0; o >>= 1) {
        if (threadIdx.x < o) {
            smin[threadIdx.x] = fminf(smin[threadIdx.x], smin[threadIdx.x+o]);
            smax[threadIdx.x] = fmaxf(smax[threadIdx.x], smax[threadIdx.x+o]);
        }
        __syncthreads();
    }
    if (threadIdx.x == 0) {
        atomicMin(&mm[2*b],   __float_as_uint(smin[0]));
        atomicMax(&mm[2*b+1], __float_as_uint(smax[0]));
    }
}

// ---------- fallback (small-ws): GN full pass + df with on-the-fly down ----------
__global__ __launch_bounds__(256) void k_gn_fb(const float* __restrict__ x,
                                               float* __restrict__ gn,
                                               unsigned* __restrict__ mm) {
    if (blockIdx.x == 0 && threadIdx.x < 2*BB)
        mm[threadIdx.x] = (threadIdx.x & 1) ? 0u : 0x7F800000u;
    __shared__ float ss[256], sq2[256];
    int bg = blockIdx.x;
    const float* p = x + (size_t)bg * 2 * HWSZ;
    float s = 0.f, q = 0.f;
    for (int i = threadIdx.x; i < 2*HWSZ; i += 256) { float v = p[i]; s += v; q += v*v; }
    ss[threadIdx.x] = s; sq2[threadIdx.x] = q;
    __syncthreads();
    for (int o = 128; o > 0; o >>= 1) {
        if (threadIdx.x < o) { ss[threadIdx.x] += ss[threadIdx.x+o]; sq2[threadIdx.x] += sq2[threadIdx.x+o]; }
        __syncthreads();
    }
    if (threadIdx.x == 0) {
        float mu  = ss[0]  / (2.f*HWSZ);
        float var = sq2[0] / (2.f*HWSZ) - mu*mu;
        gn[bg*2] = mu; gn[bg*2+1] = rsqrtf(var + 1e-5f);
    }
}
__global__ __launch_bounds__(256) void k_df_fb(const float* __restrict__ x,
                                               float* __restrict__ df,
                                               float* __restrict__ nrm,
                                               unsigned* __restrict__ mm) {
    int b = blockIdx.x / BPB;
    int pb = blockIdx.x % BPB;
    int lane = threadIdx.x & 63, wave = threadIdx.x >> 6;
    int half = lane >> 5;
    int p = pb*PBLK + wave*32 + (lane & 31);
    int h = p / WW, w = p % WW;
    float hs = fminf(fmaxf(0.5f*(float)h - 0.25f, 0.f), 95.f);
    float wsr= fminf(fmaxf(0.5f*(float)w - 0.25f, 0.f), 95.f);
    int hl = (int)hs; int hh2 = min(hl+1, 95); float fh = hs - (float)hl;
    int wl = (int)wsr; int wh2 = min(wl+1, 95); float fw = wsr - (float)wl;
    int r0 = 2*hl, r1 = 2*hh2, q0 = 2*wl, q1 = 2*wh2;
    const float* xb = x + (size_t)b*CC*HWSZ;
    float s = 0.f, sq = 0.f;
    for (int cc = 0; cc < 32; ++cc) {
        const float* pc = xb + (size_t)(32*half + cc)*HWSZ;
        float xc = pc[p];
        const float* a0 = pc + r0*WW;
        const float* a1 = pc + r1*WW;
        float v00 = 0.25f*(a0[q0]+a0[q0+1]+a0[q0+WW]+a0[q0+WW+1]);
        float v01 = 0.25f*(a0[q1]+a0[q1+1]+a0[q1+WW]+a0[q1+WW+1]);
        float v10 = 0.25f*(a1[q0]+a1[q0+1]+a1[q0+WW]+a1[q0+WW+1]);
        float v11 = 0.25f*(a1[q1]+a1[q1+1]+a1[q1+WW]+a1[q1+WW+1]);
        float t0 = (1.f-fh)*v00 + fh*v10;
        float t1 = (1.f-fh)*v01 + fh*v11;
        float du = (1.f-fw)*t0 + fw*t1;
        s  += fabsf(xc - du);
        sq += xc*xc;
    }
    s  += __shfl_xor(s, 32);
    sq += __shfl_xor(sq, 32);
    if (half == 0) { df[b*HWSZ+p] = s; nrm[b*HWSZ+p] = sqrtf(sq); }
    __shared__ float smin[256], smax[256];
    smin[threadIdx.x] = s; smax[threadIdx.x] = s;
    __syncthreads();
    for (int o = 128; o > 0; o >>= 1) {
        if (threadIdx.x < o) {
            smin[threadIdx.x] = fminf(smin[threadIdx.x], smin[threadIdx.x+o]);
            smax[threadIdx.x] = fmaxf(smax[threadIdx.x], smax[threadIdx.x+o]);
        }
        __syncthreads();
    }
    if (threadIdx.x == 0) {
        atomicMin(&mm[2*b],   __float_as_uint(smin[0]));
        atomicMax(&mm[2*b+1], __float_as_uint(smax[0]));
    }
}

// ------- fused: sims + top-k softmax + GN affine (phase 1) + MFMA FFN (phase 2) -------
// LDS: sw1 (w1 B-frags) 16K | sw2 (w2 B-frags) 16K | se (e A-frags, residual) 32K |
//      sh per-wave scratch 304 dwords each (h-repack 256, epilogue 16x17 f32) ~9.5K
__global__ __launch_bounds__(FTH, 4) void k_fused(const float* __restrict__ x,
                                                  const float* __restrict__ df,
                                                  const float* __restrict__ nrm,
                                                  const unsigned* __restrict__ mm,
                                                  const float* __restrict__ gn,
                                                  const float* __restrict__ gw,
                                                  const float* __restrict__ gb,
                                                  const float* __restrict__ w1,
                                                  const float* __restrict__ b1,
                                                  const float* __restrict__ w2,
                                                  const float* __restrict__ b2,
                                                  float* __restrict__ out) {
    __shared__ __align__(16) unsigned char lds[75264];
    unsigned* sw1 = (unsigned*)lds;                 // 4096 uints
    unsigned* sw2 = (unsigned*)(lds + 16384);       // 4096 uints
    unsigned* se  = (unsigned*)(lds + 32768);       // 8192 uints
    unsigned* sh  = (unsigned*)(lds + 65536);       // 8*304 uints

    int tid = threadIdx.x;
    // ---- stage w1 into B-frag order: (j,c) -> frag=(j>>4)*2+(c>>5),
    //      lane=((c&31)>>3)*16+(j&15), word=(c&7)/2
    for (int i = tid; i < 4096; i += FTH) {
        float2 v = ((const float2*)w1)[i];          // j = i>>5, c0 = (i&31)*2
        int j = i >> 5, cp = i & 31, c0 = cp << 1;
        int fi = ((j >> 4) << 1) + (c0 >> 5);
        int ln = (((c0 & 31) >> 3) << 4) + (j & 15);
        sw1[fi*256 + ln*4 + (cp & 3)] = pk2(v.x, v.y);
    }
    // ---- stage w2 into B-frag order: (c,j) -> frag=(j>>5)*4+(c>>4),
    //      lane=((j&31)>>3)*16+(c&15), word=(j&7)/2
    for (int i = tid; i < 4096; i += FTH) {
        float2 v = ((const float2*)w2)[i];          // c = i>>6, j0 = (i&63)*2
        int c = i >> 6, jp = i & 63, j0 = jp << 1;
        int fi = ((j0 >> 5) << 2) + (c >> 4);
        int ln = (((j0 & 31) >> 3) << 4) + (c & 15);
        sw2[fi*256 + ln*4 + (jp & 3)] = pk2(v.x, v.y);
    }

    // ================= phase 1: sims + top-k softmax + GN affine =================
    int wv = tid >> 6, lane = tid & 63;
    int half = lane >> 5;
    int pxl = wv*32 + (lane & 31);                  // 0..255 local pixel
    int blk = blockIdx.x;
    int b = blk / FBPB;
    int pb = (blk % FBPB) * FPX;
    int p = pb + pxl;
    int h = p / WW, w = p % WW;
    int cbase = 32*half;

    float dmin = __uint_as_float(mm[2*b]);
    float dmax = __uint_as_float(mm[2*b+1]);
    float dfp = (df[b*HWSZ+p] - dmin) / (dmax - dmin + 1e-8f);
    dfp = dfp * dfp;
    bool maskv = dfp > 0.3f;
    float conn = 1.f + (maskv ? fmaxf(rintf(dfp * 15.f), 0.f) : 0.f);
    bool process = conn > 1.f;
    int kk = (int)fminf(conn, 9.f);

    const float* xb = x + (size_t)b*CC*HWSZ + p;
    const int dh[9] = {-1,-1,-1, 0,0,0, 1,1,1};
    const int dwv[9] = {-1, 0, 1,-1,0,1,-1,0,1};
    bool valid[9]; int offc[9];                     // offc clamped to 0 when invalid
    #pragma unroll
    for (int j = 0; j < 9; ++j) {
        int hn = h + dh[j], wn = w + dwv[j];
        valid[j] = (hn >= 0) && (hn < HH) && (wn >= 0) && (wn < WW);
        offc[j] = valid[j] ? (dh[j]*WW + dwv[j]) : 0;
    }
    float wtc[9];
    #pragma unroll
    for (int j = 0; j < 9; ++j) wtc[j] = 0.f;

    if (process) {
        float dot[9];
        #pragma unroll
        for (int j = 0; j < 9; ++j) dot[j] = 0.f;
        for (int cc = 0; cc < 32; ++cc) {           // branch-free: loads fully pipelined
            const float* pc = xb + (size_t)(cbase + cc)*HWSZ;
            float xc = pc[0];
            #pragma unroll
            for (int j = 0; j < 9; ++j)
                dot[j] += xc * pc[offc[j]];         // garbage for invalid j (unused)
        }
        #pragma unroll
        for (int j = 0; j < 9; ++j)
            dot[j] += __shfl_xor(dot[j], 32);       // partner shares `process`
        float nc = fmaxf(nrm[b*HWSZ+p], 1e-12f);
        float sim[9];
        #pragma unroll
        for (int j = 0; j < 9; ++j) {
            float nj = fmaxf(nrm[b*HWSZ+p+offc[j]], 1e-12f);
            sim[j] = valid[j] ? dot[j] / (nc * nj) : 0.f;  // zero-pad => exact 0
        }
        float S = 0.f;
        float wt[9];
        #pragma unroll
        for (int j = 0; j < 9; ++j) {
            int rank = 0;
            #pragma unroll
            for (int l = 0; l < 9; ++l)
                rank += (sim[l] > sim[j]) || (sim[l] == sim[j] && l < j);
            float ex = (rank < kk) ? expf(sim[j]) : 0.f;  // == stable argsort(-sim)
            wt[j] = ex; S += ex;                    // invalid j contributes exp(0) to S
        }
        float inv = 1.f / fmaxf(S, 1e-12f);
        #pragma unroll
        for (int j = 0; j < 9; ++j)
            wtc[j] = valid[j] ? wt[j] * inv : 0.f;  // zero patch => zero contribution
    }

    float e[32];
    for (int cc = 0; cc < 32; ++cc) {
        int c = cbase + cc;
        const float* pc = xb + (size_t)c*HWSZ;
        float xc = pc[0];
        float oc;
        if (process) {
            float a = 0.f;
            #pragma unroll
            for (int j = 0; j < 9; ++j)
                a += wtc[j] * pc[offc[j]];          // branch-free
            oc = a;
        } else oc = xc;
        int g = c >> 1;
        float mu = gn[(b*GG+g)*2], is = gn[(b*GG+g)*2+1];
        e[cc] = oc + (xc - mu) * is * gw[c] + gb[c];
    }

    // write e into A-frag order: pixel pxl (tt=pxl>>4, m=pxl&15), ch chunk kc=half
    {
        int tt = pxl >> 4, m = pxl & 15;
        unsigned* dst = se + ((tt*2 + half)*256) + m*4;
        #pragma unroll
        for (int q = 0; q < 4; ++q) {
            uint4 u;
            u.x = pk2(e[q*8+0], e[q*8+1]);
            u.y = pk2(e[q*8+2], e[q*8+3]);
            u.z = pk2(e[q*8+4], e[q*8+5]);
            u.w = pk2(e[q*8+6], e[q*8+7]);
            *(uint4*)(dst + q*64) = u;              // lane q*16+m of the frag
        }
    }
    __syncthreads();

    // ================= phase 2: MFMA FFN =================
    int qd = lane >> 4, n16 = lane & 15;
    float b1v[8], b2v[4];
    #pragma unroll
    for (int nt = 0; nt < 8; ++nt) b1v[nt] = b1[nt*16 + n16];
    #pragma unroll
    for (int n2 = 0; n2 < 4; ++n2) b2v[n2] = b2[n2*16 + n16];

    unsigned* shwv = sh + wv*304;                   // per-wave scratch (304 dwords)
    unsigned short* shw = (unsigned short*)shwv;
    float* sct = (float*)shwv;                      // epilogue 16x17 f32 view
    float* outb = out + (size_t)b*CC*HWSZ;
    unsigned short* seu = (unsigned short*)se;

    for (int t = 0; t < 2; ++t) {
        int ttg = wv*2 + t;                         // tile of 16 pixels
        uint4 a0 = *(uint4*)(se + ((ttg*2+0)*256) + lane*4);
        uint4 a1 = *(uint4*)(se + ((ttg*2+1)*256) + lane*4);
        f32x4 D1[8];
        #pragma unroll
        for (int nt = 0; nt < 8; ++nt) D1[nt] = (f32x4){0.f,0.f,0.f,0.f};
        #pragma unroll
        for (int nt = 0; nt < 8; ++nt) {
            uint4 bk0 = *(uint4*)(sw1 + ((nt*2+0)*256) + lane*4);
            uint4 bk1 = *(uint4*)(sw1 + ((nt*2+1)*256) + lane*4);
            D1[nt] = __builtin_amdgcn_mfma_f32_16x16x32_bf16(u4s8(a0), u4s8(bk0), D1[nt], 0, 0, 0);
            D1[nt] = __builtin_amdgcn_mfma_f32_16x16x32_bf16(u4s8(a1), u4s8(bk1), D1[nt], 0, 0, 0);
        }
        f32x4 D2[4];
        #pragma unroll
        for (int n2 = 0; n2 < 4; ++n2) D2[n2] = (f32x4){0.f,0.f,0.f,0.f};
        for (int kc2 = 0; kc2 < 4; ++kc2) {
            // relu(h) chunk (hidden kc2*32..+31) -> wave scratch in A-frag order
            #pragma unroll
            for (int h2 = 0; h2 < 2; ++h2) {
                int nt = kc2*2 + h2;
                #pragma unroll
                for (int r = 0; r < 4; ++r) {
                    float hval = fmaxf(D1[nt][r] + b1v[nt], 0.f);
                    int mrow = qd*4 + r;            // pixel row in tile
                    int k = h2*16 + n16;            // hid within 32-chunk
                    shw[((k >> 3)*16 + mrow)*8 + (k & 7)] = f2bf(hval);
                }
            }
            uint4 ah = *(uint4*)(shwv + lane*4);    // same-wave LDS RAW: in-order
            #pragma unroll
            for (int n2 = 0; n2 < 4; ++n2) {
                uint4 bb = *(uint4*)(sw2 + ((kc2*4 + n2)*256) + lane*4);
                D2[n2] = __builtin_amdgcn_mfma_f32_16x16x32_bf16(u4s8(ah), u4s8(bb), D2[n2], 0, 0, 0);
            }
        }
        // epilogue: out = D2 + residual(e) + b2, transposed via wave LDS for
        // full-line coalesced stores (was 3.4x write amplification)
        #pragma unroll
        for (int n2 = 0; n2 < 4; ++n2) {
            int c = n2*16 + n16;
            int kc = c >> 5, qq = (c & 31) >> 3, jj = c & 7;
            #pragma unroll
            for (int r = 0; r < 4; ++r) {
                int pxt = qd*4 + r;
                float resid = bf2f(seu[(((ttg*2+kc)*64 + qq*16 + pxt))*8 + jj]);
                sct[pxt*17 + n16] = D2[n2][r] + resid + b2v[n2];
            }
            // read back transposed: quarter-wave per channel, 16 consecutive px
            int c_l = lane >> 4;                    // 0..3
            int px_l = lane & 15;
            #pragma unroll
            for (int cc2 = 0; cc2 < 4; ++cc2) {
                int cs = n2*16 + cc2*4 + c_l;
                float val = sct[px_l*17 + cc2*4 + c_l];
                outb[(size_t)cs*HWSZ + pb + ttg*16 + px_l] = val;
            }
        }
    }
}

extern "C" void kernel_launch(void* const* d_in, const int* in_sizes, int n_in,
                              void* d_out, int out_size, void* d_ws, size_t ws_size,
                              hipStream_t stream) {
    const float* x  = (const float*)d_in[0];
    const float* gw = (const float*)d_in[1];
    const float* gb = (const float*)d_in[2];
    const float* w1 = (const float*)d_in[3];
    const float* b1 = (const float*)d_in[4];
    const float* w2 = (const float*)d_in[5];
    const float* b2 = (const float*)d_in[6];
    float* out = (float*)d_out;

    const size_t NEED = (size_t)(2359296 + 147456 + 147456 + 256 + 256 + 8) * 4;
    float* ws = (float*)d_ws;
    if (ws_size >= NEED) {
        float* xd    = ws;
        float* df    = xd + 2359296;
        float* nrm   = df + 147456;
        float* gnacc = nrm + 147456;
        float* gn    = gnacc + 256;
        unsigned* mm = (unsigned*)(gn + 256);
        k_zero    <<<1, 256, 0, stream>>>(gnacc, mm);
        k_down    <<<(BB*CC*HD*WD)/256, 256, 0, stream>>>(x, xd, gnacc);
        k_gn_final<<<1, 128, 0, stream>>>(gnacc, gn);
        k_df      <<<BB*BPB, 256, 0, stream>>>(x, xd, df, nrm, mm);
        k_fused   <<<BB*FBPB, FTH, 0, stream>>>(x, df, nrm, mm, gn, gw, gb,
                                                w1, b1, w2, b2, out);
    } else {
        float* df    = ws;
        float* nrm   = df + 147456;
        float* gn    = nrm + 147456;
        unsigned* mm = (unsigned*)(gn + 256);
        k_gn_fb<<<BB*GG, 256, 0, stream>>>(x, gn, mm);
        k_df_fb<<<BB*BPB, 256, 0, stream>>>(x, df, nrm, mm);
        k_fused<<<BB*FBPB, FTH, 0, stream>>>(x, df, nrm, mm, gn, gw, gb,
                                             w1, b1, w2, b2, out);
    }
}

// Round 9
// 246.904 us; speedup vs baseline: 4.6513x; 1.4562x over previous
//
#include <hip/hip_runtime.h>
#include <hip/hip_bf16.h>

#define BB 4
#define CC 64
#define HH 192
#define WW 192
#define HWSZ (HH*WW)          // 36864
#define HD 96
#define WD 96
#define GG 32
// fused kernel geometry: 512 threads, 128 pixels (4 threads/pixel in phase 1)
#define FTH 512
#define FPX 128
#define FBPB (HWSZ/FPX)       // 288 blocks per batch; grid 1152
// df kernel geometry: 256 threads, 128 pixels
#define PBLK 128
#define BPB (HWSZ/PBLK)       // 288 blocks per batch; grid 1152

typedef short short8 __attribute__((ext_vector_type(8)));
typedef float f32x4  __attribute__((ext_vector_type(4)));

__device__ __forceinline__ unsigned short f2bf(float f) {
    unsigned u = __float_as_uint(f);
    return (unsigned short)((u + 0x7FFFu + ((u >> 16) & 1u)) >> 16);
}
__device__ __forceinline__ float bf2f(unsigned short s) {
    return __uint_as_float(((unsigned)s) << 16);
}
__device__ __forceinline__ unsigned pk2(float a, float b) {
    return (unsigned)f2bf(a) | ((unsigned)f2bf(b) << 16);
}
__device__ __forceinline__ short8 u4s8(uint4 u) {
    union { uint4 a; short8 b; } cvt; cvt.a = u; return cvt.b;
}

// ---------------- zero gn accumulators + init mm ----------------
__global__ void k_zero(float* __restrict__ gnacc, unsigned* __restrict__ mm) {
    int t = threadIdx.x;
    if (t < 256) gnacc[t] = 0.f;
    if (t < 2*BB) mm[t] = (t & 1) ? 0u : 0x7F800000u; // even=min(+inf bits), odd=max(0)
}

// ---- pre-pass: pack w1/w2 into MFMA B-frag order (bf16) in ws ----
// wf[0..4095]   : w1 frags  (j,c) -> frag=(j>>4)*2+(c>>5), lane=((c&31)>>3)*16+(j&15), word=(c&7)/2
// wf[4096..8191]: w2 frags  (c,j) -> frag=(j>>5)*4+(c>>4), lane=((j&31)>>3)*16+(c&15), word=(j&7)/2
__global__ __launch_bounds__(512) void k_wprep(const float* __restrict__ w1,
                                               const float* __restrict__ w2,
                                               unsigned* __restrict__ wf) {
    int i = blockIdx.x*512 + threadIdx.x;     // grid 16 -> 8192
    if (i < 4096) {
        float2 v = ((const float2*)w1)[i];    // j = i>>5, c0 = (i&31)*2
        int j = i >> 5, cp = i & 31, c0 = cp << 1;
        int fi = ((j >> 4) << 1) + (c0 >> 5);
        int ln = (((c0 & 31) >> 3) << 4) + (j & 15);
        wf[fi*256 + ln*4 + (cp & 3)] = pk2(v.x, v.y);
    } else {
        int i2 = i - 4096;
        float2 v = ((const float2*)w2)[i2];   // c = i2>>6, j0 = (i2&63)*2
        int c = i2 >> 6, jp = i2 & 63, j0 = jp << 1;
        int fi = ((j0 >> 5) << 2) + (c >> 4);
        int ln = (((j0 & 31) >> 3) << 4) + (c & 15);
        wf[4096 + fi*256 + ln*4 + (jp & 3)] = pk2(v.x, v.y);
    }
}

// ---- 2x bilinear down (= 2x2 average) + fused GroupNorm partial sums ----
__global__ __launch_bounds__(256) void k_down(const float* __restrict__ x,
                                              float* __restrict__ xd,
                                              float* __restrict__ gnacc) {
    int idx = blockIdx.x * 256 + threadIdx.x;        // B*C*96*96
    int xw = idx % WD; int t = idx / WD;
    int y = t % HD;   int bc = t / HD;               // uniform per block
    const float* p = x + (size_t)bc * HWSZ + (2*y)*WW + 2*xw;
    float p0 = p[0], p1 = p[1], p2 = p[WW], p3 = p[WW+1];
    xd[idx] = 0.25f*((p0+p2) + (p1+p3));
    float s  = (p0+p1) + (p2+p3);
    float sq = (p0*p0+p1*p1) + (p2*p2+p3*p3);
    __shared__ float ss[256], sq2[256];
    ss[threadIdx.x] = s; sq2[threadIdx.x] = sq;
    __syncthreads();
    for (int o = 128; o > 0; o >>= 1) {
        if (threadIdx.x < o) {
            ss[threadIdx.x]  += ss[threadIdx.x+o];
            sq2[threadIdx.x] += sq2[threadIdx.x+o];
        }
        __syncthreads();
    }
    if (threadIdx.x == 0) {
        int b = bc >> 6, g = (bc & 63) >> 1;
        atomicAdd(&gnacc[2*(b*GG+g)],   ss[0]);
        atomicAdd(&gnacc[2*(b*GG+g)+1], sq2[0]);
    }
}

// ---------------- finalize GroupNorm stats ----------------
__global__ void k_gn_final(const float* __restrict__ gnacc, float* __restrict__ gn) {
    int t = threadIdx.x;
    if (t < BB*GG) {
        float n = 2.f*HWSZ;
        float mu  = gnacc[2*t] / n;
        float var = gnacc[2*t+1] / n - mu*mu;
        gn[2*t]   = mu;
        gn[2*t+1] = rsqrtf(var + 1e-5f);
    }
}

// XCD-slab swizzle for 1152-block grids: presumed xcd = bid%8; give each XCD a
// contiguous 144-block slab so its 4MB L2 holds that slab's x rows.
__device__ __forceinline__ int swz1152(int bid) {
    return (bid & 7) * 144 + (bid >> 3);
}

// ---- df = sum_c |x - up(xd)| using precomputed xd; also ||x||_c ----
__global__ __launch_bounds__(256) void k_df(const float* __restrict__ x,
                                            const float* __restrict__ xd,
                                            float* __restrict__ df,
                                            float* __restrict__ nrm,
                                            unsigned* __restrict__ mm) {
    int virt = swz1152(blockIdx.x);
    int b = virt / BPB;
    int pb = (virt % BPB) * PBLK;
    int lane = threadIdx.x & 63, wave = threadIdx.x >> 6;
    int half = lane >> 5;
    int p = pb + wave*32 + (lane & 31);
    int h = p / WW, w = p % WW;
    float hs = fminf(fmaxf(0.5f*(float)h - 0.25f, 0.f), 95.f);
    float wsr= fminf(fmaxf(0.5f*(float)w - 0.25f, 0.f), 95.f);
    int hl = (int)hs; int hh2 = min(hl+1, 95); float fh = hs - (float)hl;
    int wl = (int)wsr; int wh2 = min(wl+1, 95); float fw = wsr - (float)wl;
    bool pair = (wh2 == wl + 1);

    const float* xb = x + (size_t)b*CC*HWSZ;
    const float* db = xd + (size_t)(b*CC + 32*half)*(HD*WD);
    float s = 0.f, sq = 0.f;
    #pragma unroll 4
    for (int cc = 0; cc < 32; ++cc) {
        const float* pc = xb + (size_t)(32*half + cc)*HWSZ;
        float xc = pc[p];
        const float* d = db + cc*(HD*WD);
        float v00, v01, v10, v11;
        if (pair) {
            float2 a = *(const float2*)(d + hl*WD + wl);
            float2 bqq = *(const float2*)(d + hh2*WD + wl);
            v00 = a.x; v01 = a.y; v10 = bqq.x; v11 = bqq.y;
        } else {
            v00 = d[hl*WD+wl];  v01 = d[hl*WD+wh2];
            v10 = d[hh2*WD+wl]; v11 = d[hh2*WD+wh2];
        }
        float t0 = (1.f-fh)*v00 + fh*v10;
        float t1 = (1.f-fh)*v01 + fh*v11;
        float du = (1.f-fw)*t0 + fw*t1;
        s  += fabsf(xc - du);
        sq += xc*xc;
    }
    s  += __shfl_xor(s, 32);
    sq += __shfl_xor(sq, 32);
    if (half == 0) {
        df[b*HWSZ+p]  = s;
        nrm[b*HWSZ+p] = sqrtf(sq);
    }
    __shared__ float smin[256], smax[256];
    smin[threadIdx.x] = s; smax[threadIdx.x] = s;
    __syncthreads();
    for (int o = 128; o > 0; o >>= 1) {
        if (threadIdx.x < o) {
            smin[threadIdx.x] = fminf(smin[threadIdx.x], smin[threadIdx.x+o]);
            smax[threadIdx.x] = fmaxf(smax[threadIdx.x], smax[threadIdx.x+o]);
        }
        __syncthreads();
    }
    if (threadIdx.x == 0) {
        atomicMin(&mm[2*b],   __float_as_uint(smin[0]));
        atomicMax(&mm[2*b+1], __float_as_uint(smax[0]));
    }
}

// ---------- fallback (small-ws): GN full pass + df with on-the-fly down ----------
__global__ __launch_bounds__(256) void k_gn_fb(const float* __restrict__ x,
                                               float* __restrict__ gn,
                                               unsigned* __restrict__ mm) {
    if (blockIdx.x == 0 && threadIdx.x < 2*BB)
        mm[threadIdx.x] = (threadIdx.x & 1) ? 0u : 0x7F800000u;
    __shared__ float ss[256], sq2[256];
    int bg = blockIdx.x;
    const float* p = x + (size_t)bg * 2 * HWSZ;
    float s = 0.f, q = 0.f;
    for (int i = threadIdx.x; i < 2*HWSZ; i += 256) { float v = p[i]; s += v; q += v*v; }
    ss[threadIdx.x] = s; sq2[threadIdx.x] = q;
    __syncthreads();
    for (int o = 128; o > 0; o >>= 1) {
        if (threadIdx.x < o) { ss[threadIdx.x] += ss[threadIdx.x+o]; sq2[threadIdx.x] += sq2[threadIdx.x+o]; }
        __syncthreads();
    }
    if (threadIdx.x == 0) {
        float mu  = ss[0]  / (2.f*HWSZ);
        float var = sq2[0] / (2.f*HWSZ) - mu*mu;
        gn[bg*2] = mu; gn[bg*2+1] = rsqrtf(var + 1e-5f);
    }
}
__global__ __launch_bounds__(256) void k_df_fb(const float* __restrict__ x,
                                               float* __restrict__ df,
                                               float* __restrict__ nrm,
                                               unsigned* __restrict__ mm) {
    int virt = swz1152(blockIdx.x);
    int b = virt / BPB;
    int pb = (virt % BPB) * PBLK;
    int lane = threadIdx.x & 63, wave = threadIdx.x >> 6;
    int half = lane >> 5;
    int p = pb + wave*32 + (lane & 31);
    int h = p / WW, w = p % WW;
    float hs = fminf(fmaxf(0.5f*(float)h - 0.25f, 0.f), 95.f);
    float wsr= fminf(fmaxf(0.5f*(float)w - 0.25f, 0.f), 95.f);
    int hl = (int)hs; int hh2 = min(hl+1, 95); float fh = hs - (float)hl;
    int wl = (int)wsr; int wh2 = min(wl+1, 95); float fw = wsr - (float)wl;
    int r0 = 2*hl, r1 = 2*hh2, q0 = 2*wl, q1 = 2*wh2;
    const float* xb = x + (size_t)b*CC*HWSZ;
    float s = 0.f, sq = 0.f;
    for (int cc = 0; cc < 32; ++cc) {
        const float* pc = xb + (size_t)(32*half + cc)*HWSZ;
        float xc = pc[p];
        const float* a0 = pc + r0*WW;
        const float* a1 = pc + r1*WW;
        float v00 = 0.25f*(a0[q0]+a0[q0+1]+a0[q0+WW]+a0[q0+WW+1]);
        float v01 = 0.25f*(a0[q1]+a0[q1+1]+a0[q1+WW]+a0[q1+WW+1]);
        float v10 = 0.25f*(a1[q0]+a1[q0+1]+a1[q0+WW]+a1[q0+WW+1]);
        float v11 = 0.25f*(a1[q1]+a1[q1+1]+a1[q1+WW]+a1[q1+WW+1]);
        float t0 = (1.f-fh)*v00 + fh*v10;
        float t1 = (1.f-fh)*v01 + fh*v11;
        float du = (1.f-fw)*t0 + fw*t1;
        s  += fabsf(xc - du);
        sq += xc*xc;
    }
    s  += __shfl_xor(s, 32);
    sq += __shfl_xor(sq, 32);
    if (half == 0) { df[b*HWSZ+p] = s; nrm[b*HWSZ+p] = sqrtf(sq); }
    __shared__ float smin[256], smax[256];
    smin[threadIdx.x] = s; smax[threadIdx.x] = s;
    __syncthreads();
    for (int o = 128; o > 0; o >>= 1) {
        if (threadIdx.x < o) {
            smin[threadIdx.x] = fminf(smin[threadIdx.x], smin[threadIdx.x+o]);
            smax[threadIdx.x] = fmaxf(smax[threadIdx.x], smax[threadIdx.x+o]);
        }
        __syncthreads();
    }
    if (threadIdx.x == 0) {
        atomicMin(&mm[2*b],   __float_as_uint(smin[0]));
        atomicMax(&mm[2*b+1], __float_as_uint(smax[0]));
    }
}

// ------- fused: sims + top-k softmax + GN affine (phase 1) + MFMA FFN (phase 2) -------
// 512 threads, 128 px/block (4 threads/px). LDS 24576 B:
//   se [0..16K)  : e A-frags (8 tiles x 2 kc), bf16; residual source
//   sh [16K..24K): per-wave h-repack scratch (1 KB each)
//   stg (aliased over se+sh after sync): fp32 staging [32 ch][132] for coalesced stores
// Weights come from global wf (frag-ordered bf16, L2-resident).
__global__ __launch_bounds__(FTH, 4) void k_fused(const float* __restrict__ x,
                                                  const float* __restrict__ df,
                                                  const float* __restrict__ nrm,
                                                  const unsigned* __restrict__ mm,
                                                  const float* __restrict__ gn,
                                                  const float* __restrict__ gw,
                                                  const float* __restrict__ gb,
                                                  const unsigned* __restrict__ wf,
                                                  const float* __restrict__ b1,
                                                  const float* __restrict__ b2,
                                                  float* __restrict__ out) {
    __shared__ __align__(16) unsigned char lds[24576];
    unsigned* se = (unsigned*)lds;                  // 4096 uints
    unsigned* sh = (unsigned*)(lds + 16384);        // 2048 uints

    int tid = threadIdx.x;
    int wv = tid >> 6, lane = tid & 63;
    int q = lane >> 4, m = lane & 15;               // quarter (ch group), pixel row

    int virt = swz1152(blockIdx.x);
    int b = virt / FBPB;
    int pb = (virt % FBPB) * FPX;
    int pxl = wv*16 + m;                            // 0..127 local pixel
    int p = pb + pxl;
    int h = p / WW, w = p % WW;
    int cbase = q*16;

    // ================= phase 1 =================
    float dmin = __uint_as_float(mm[2*b]);
    float dmax = __uint_as_float(mm[2*b+1]);
    float dfp = (df[b*HWSZ+p] - dmin) / (dmax - dmin + 1e-8f);
    dfp = dfp * dfp;
    bool maskv = dfp > 0.3f;
    float conn = 1.f + (maskv ? fmaxf(rintf(dfp * 15.f), 0.f) : 0.f);
    bool process = conn > 1.f;
    int kk = (int)fminf(conn, 9.f);

    const float* xb = x + (size_t)b*CC*HWSZ + p;
    const int dhv[9] = {-1,-1,-1, 0,0,0, 1,1,1};
    const int dwv[9] = {-1, 0, 1,-1,0,1,-1,0,1};
    bool valid[9]; int offc[9];
    #pragma unroll
    for (int j = 0; j < 9; ++j) {
        int hn = h + dhv[j], wn = w + dwv[j];
        valid[j] = (hn >= 0) && (hn < HH) && (wn >= 0) && (wn < WW);
        offc[j] = valid[j] ? (dhv[j]*WW + dwv[j]) : 0;
    }
    float wtc[9];
    #pragma unroll
    for (int j = 0; j < 9; ++j) wtc[j] = 0.f;

    if (process) {
        float dot[9];
        #pragma unroll
        for (int j = 0; j < 9; ++j) dot[j] = 0.f;
        for (int cc = 0; cc < 16; ++cc) {           // branch-free, pipelined
            const float* pc = xb + (size_t)(cbase + cc)*HWSZ;
            float xc = pc[0];
            #pragma unroll
            for (int j = 0; j < 9; ++j)
                dot[j] += xc * pc[offc[j]];
        }
        #pragma unroll
        for (int j = 0; j < 9; ++j) {
            dot[j] += __shfl_xor(dot[j], 16);       // 4 quarters share px
            dot[j] += __shfl_xor(dot[j], 32);
        }
        float nc = fmaxf(nrm[b*HWSZ+p], 1e-12f);
        float sim[9];
        #pragma unroll
        for (int j = 0; j < 9; ++j) {
            float nj = fmaxf(nrm[b*HWSZ+p+offc[j]], 1e-12f);
            sim[j] = valid[j] ? dot[j] / (nc * nj) : 0.f;
        }
        float S = 0.f;
        float wt[9];
        #pragma unroll
        for (int j = 0; j < 9; ++j) {
            int rank = 0;
            #pragma unroll
            for (int l = 0; l < 9; ++l)
                rank += (sim[l] > sim[j]) || (sim[l] == sim[j] && l < j);
            float ex = (rank < kk) ? expf(sim[j]) : 0.f;  // stable argsort(-sim) top-k
            wt[j] = ex; S += ex;
        }
        float inv = 1.f / fmaxf(S, 1e-12f);
        #pragma unroll
        for (int j = 0; j < 9; ++j)
            wtc[j] = valid[j] ? wt[j] * inv : 0.f;
    }

    float e[16];
    for (int cc = 0; cc < 16; ++cc) {
        int c = cbase + cc;
        const float* pc = xb + (size_t)c*HWSZ;
        float xc = pc[0];
        float oc;
        if (process) {
            float a = 0.f;
            #pragma unroll
            for (int j = 0; j < 9; ++j)
                a += wtc[j] * pc[offc[j]];
            oc = a;
        } else oc = xc;
        int g = c >> 1;
        float mu = gn[(b*GG+g)*2], is = gn[(b*GG+g)*2+1];
        e[cc] = oc + (xc - mu) * is * gw[c] + gb[c];
    }

    // e -> A-frag order: tile wv, kc=q>>1, k = 16*(q&1)+j
    {
        int kc = q >> 1, qo = q & 1;
        unsigned* dst = se + (wv*2 + kc)*256;
        int la = 32*qo + m;
        uint4 ua, ub;
        ua.x = pk2(e[0],e[1]);  ua.y = pk2(e[2],e[3]);
        ua.z = pk2(e[4],e[5]);  ua.w = pk2(e[6],e[7]);
        ub.x = pk2(e[8],e[9]);  ub.y = pk2(e[10],e[11]);
        ub.z = pk2(e[12],e[13]); ub.w = pk2(e[14],e[15]);
        *(uint4*)(dst + la*4)      = ua;
        *(uint4*)(dst + (la+16)*4) = ub;
    }
    __syncthreads();

    // ================= phase 2: MFMA FFN (tile = wv, 16 px) =================
    const unsigned* wf1g = wf;
    const unsigned* wf2g = wf + 4096;
    int n16 = m;
    float b1v[8], b2v[4];
    #pragma unroll
    for (int nt = 0; nt < 8; ++nt) b1v[nt] = b1[nt*16 + n16];
    #pragma unroll
    for (int n2 = 0; n2 < 4; ++n2) b2v[n2] = b2[n2*16 + n16];

    uint4 a0 = *(uint4*)(se + (wv*2+0)*256 + lane*4);
    uint4 a1 = *(uint4*)(se + (wv*2+1)*256 + lane*4);
    f32x4 D1[8];
    #pragma unroll
    for (int nt = 0; nt < 8; ++nt) D1[nt] = (f32x4){0.f,0.f,0.f,0.f};
    #pragma unroll
    for (int nt = 0; nt < 8; ++nt) {
        uint4 bk0 = *(const uint4*)(wf1g + (nt*2+0)*256 + lane*4);
        uint4 bk1 = *(const uint4*)(wf1g + (nt*2+1)*256 + lane*4);
        D1[nt] = __builtin_amdgcn_mfma_f32_16x16x32_bf16(u4s8(a0), u4s8(bk0), D1[nt], 0, 0, 0);
        D1[nt] = __builtin_amdgcn_mfma_f32_16x16x32_bf16(u4s8(a1), u4s8(bk1), D1[nt], 0, 0, 0);
    }
    f32x4 D2[4];
    #pragma unroll
    for (int n2 = 0; n2 < 4; ++n2) D2[n2] = (f32x4){0.f,0.f,0.f,0.f};
    unsigned* shwv = sh + wv*256;
    unsigned short* shw = (unsigned short*)shwv;
    for (int kc2 = 0; kc2 < 4; ++kc2) {
        #pragma unroll
        for (int h2 = 0; h2 < 2; ++h2) {
            int nt = kc2*2 + h2;
            #pragma unroll
            for (int r = 0; r < 4; ++r) {
                float hval = fmaxf(D1[nt][r] + b1v[nt], 0.f);
                int mrow = q*4 + r;
                int k = h2*16 + n16;
                shw[((k >> 3)*16 + mrow)*8 + (k & 7)] = f2bf(hval);
            }
        }
        uint4 ah = *(uint4*)(shwv + lane*4);        // same-wave LDS RAW: in-order
        #pragma unroll
        for (int n2 = 0; n2 < 4; ++n2) {
            uint4 bb = *(const uint4*)(wf2g + (kc2*4 + n2)*256 + lane*4);
            D2[n2] = __builtin_amdgcn_mfma_f32_16x16x32_bf16(u4s8(ah), u4s8(bb), D2[n2], 0, 0, 0);
        }
    }
    // residual + b2 into regs
    float vals[4][4];
    unsigned short* seu = (unsigned short*)se;
    #pragma unroll
    for (int n2 = 0; n2 < 4; ++n2) {
        int c = n2*16 + n16;
        int kc = c >> 5, qq = (c & 31) >> 3, jj = c & 7;
        #pragma unroll
        for (int r = 0; r < 4; ++r) {
            int pxt = q*4 + r;
            float resid = bf2f(seu[((wv*2+kc)*64 + qq*16 + pxt)*8 + jj]);
            vals[n2][r] = D2[n2][r] + resid + b2v[n2];
        }
    }
    __syncthreads();                                 // se dead; reuse as staging

    // ---- coalesced epilogue: 2 rounds of 32 channels via fp32 staging ----
    float* stg = (float*)lds;                        // [32 rows][stride 132]
    float* outb = out + (size_t)b*CC*HWSZ;
    #pragma unroll
    for (int g = 0; g < 2; ++g) {
        #pragma unroll
        for (int hn2 = 0; hn2 < 2; ++hn2) {
            int n2 = 2*g + hn2;
            int row = (n2 & 1)*16 + n16;
            float4 v4 = make_float4(vals[n2][0], vals[n2][1], vals[n2][2], vals[n2][3]);
            *(float4*)&stg[row*132 + wv*16 + q*4] = v4;
        }
        __syncthreads();
        #pragma unroll
        for (int rr = 0; rr < 2; ++rr) {
            int r0 = (wv*2 + rr)*2 + (lane >> 5);    // 0..31
            int px4 = (lane & 31) * 4;
            float4 v = *(float4*)&stg[r0*132 + px4];
            *(float4*)&outb[(size_t)(g*32 + r0)*HWSZ + pb + px4] = v;
        }
        if (g == 0) __syncthreads();
    }
}

extern "C" void kernel_launch(void* const* d_in, const int* in_sizes, int n_in,
                              void* d_out, int out_size, void* d_ws, size_t ws_size,
                              hipStream_t stream) {
    const float* x  = (const float*)d_in[0];
    const float* gw = (const float*)d_in[1];
    const float* gb = (const float*)d_in[2];
    const float* w1 = (const float*)d_in[3];
    const float* b1 = (const float*)d_in[4];
    const float* w2 = (const float*)d_in[5];
    const float* b2 = (const float*)d_in[6];
    float* out = (float*)d_out;

    const size_t NEED = (size_t)(2359296 + 147456 + 147456 + 256 + 256 + 8 + 8192) * 4;
    float* ws = (float*)d_ws;
    if (ws_size >= NEED) {
        float* xd    = ws;
        float* df    = xd + 2359296;
        float* nrm   = df + 147456;
        float* gnacc = nrm + 147456;
        float* gn    = gnacc + 256;
        unsigned* mm = (unsigned*)(gn + 256);
        unsigned* wf = mm + 8;
        k_zero    <<<1, 256, 0, stream>>>(gnacc, mm);
        k_wprep   <<<16, 512, 0, stream>>>(w1, w2, wf);
        k_down    <<<(BB*CC*HD*WD)/256, 256, 0, stream>>>(x, xd, gnacc);
        k_gn_final<<<1, 128, 0, stream>>>(gnacc, gn);
        k_df      <<<BB*BPB, 256, 0, stream>>>(x, xd, df, nrm, mm);
        k_fused   <<<BB*FBPB, FTH, 0, stream>>>(x, df, nrm, mm, gn, gw, gb,
                                                wf, b1, b2, out);
    } else {
        // small fallback: df | nrm | gn | mm | wf  (~1.2 MB)
        float* df    = ws;
        float* nrm   = df + 147456;
        float* gn    = nrm + 147456;
        unsigned* mm = (unsigned*)(gn + 256);
        unsigned* wf = mm + 8;
        k_wprep<<<16, 512, 0, stream>>>(w1, w2, wf);
        k_gn_fb<<<BB*GG, 256, 0, stream>>>(x, gn, mm);
        k_df_fb<<<BB*BPB, 256, 0, stream>>>(x, df, nrm, mm);
        k_fused<<<BB*FBPB, FTH, 0, stream>>>(x, df, nrm, mm, gn, gw, gb,
                                             wf, b1, b2, out);
    }
}